// Round 2
// baseline (61085.809 us; speedup 1.0000x reference)
//
#include <hip/hip_runtime.h>
#include <cstdint>
#include <cstddef>

#define BB 32
#define TT 512

// ---------------- flag-based grid barrier ----------------
// flags: one slot per block (zeroed per launch-slot). Arrival: release-store
// phase. Wait: relaxed agent-scope poll (atomics at agent scope read through
// to the coherence point, so no per-poll cache invalidate). One threadfence
// after completion invalidates L1/L2 so fresh h is read (cross-XCD).
__device__ __forceinline__ void gbar(unsigned* flags, int nblk, unsigned phase) {
  __syncthreads();
  if (threadIdx.x == 0)
    __hip_atomic_store(&flags[blockIdx.x], phase, __ATOMIC_RELEASE, __HIP_MEMORY_SCOPE_AGENT);
  const int tid = threadIdx.x;
  for (;;) {
    int ok = 1;
    if (tid < nblk)
      ok = (__hip_atomic_load(&flags[tid], __ATOMIC_RELAXED, __HIP_MEMORY_SCOPE_AGENT) >= phase);
    if (__syncthreads_count(ok) == (int)blockDim.x) break;
    __builtin_amdgcn_s_sleep(2);
  }
  __threadfence();
}

// ---------------- transpose R[U,3U] -> Rt[3U,U] ----------------
__global__ __launch_bounds__(256) void transpose_k(const float* __restrict__ in,
                                                   float* __restrict__ outp,
                                                   int rows /*U*/, int cols /*3U*/) {
  int idx = blockIdx.x * 256 + threadIdx.x;
  int total = rows * cols;
  if (idx < total) {
    int k = idx % rows;
    int c = idx / rows;
    outp[idx] = in[(size_t)k * cols + c];
  }
}

// ---------------- fp32 tiled GEMM: C[M,N] = A[M,K] @ W[K,N] + bias[N] ----------------
// If t0 >= 0, A row r maps to original row ((r>>tcLog2)<<9) + t0 + (r & (Tc-1))
// (chunked view of x[B,T,F]); else rows are contiguous with stride lda.
__global__ __launch_bounds__(256) void gemm_bias(const float* __restrict__ A, int lda,
                                                 const float* __restrict__ W,
                                                 const float* __restrict__ bias,
                                                 float* __restrict__ C,
                                                 int M, int N, int K,
                                                 int t0, int tcLog2) {
  __shared__ float As[16][68];
  __shared__ float Ws[16][68];
  const int bm = blockIdx.y * 64;
  const int bn = blockIdx.x * 64;
  const int tx = threadIdx.x & 15;   // n dir
  const int ty = threadIdx.x >> 4;   // m dir
  const int tcMask = (1 << tcLog2) - 1;
  float acc[4][4] = {};

  for (int k0 = 0; k0 < K; k0 += 16) {
    for (int i = threadIdx.x; i < 64 * 16; i += 256) {
      int r = i >> 4, c = i & 15;
      int kk = k0 + c;
      int rg = bm + r;
      size_t arow;
      if (t0 >= 0)
        arow = ((size_t)(rg >> tcLog2) << 9) + t0 + (rg & tcMask);
      else
        arow = (size_t)rg;
      As[c][r] = (kk < K) ? A[arow * lda + kk] : 0.f;
    }
    for (int i = threadIdx.x; i < 16 * 64; i += 256) {
      int r = i >> 6, c = i & 63;
      int kk = k0 + r, nn = bn + c;
      Ws[r][c] = (kk < K && nn < N) ? W[(size_t)kk * N + nn] : 0.f;
    }
    __syncthreads();
#pragma unroll
    for (int kk = 0; kk < 16; ++kk) {
      float4 av = *(const float4*)&As[kk][ty * 4];
      float4 bv = *(const float4*)&Ws[kk][tx * 4];
      float a[4] = {av.x, av.y, av.z, av.w};
      float b[4] = {bv.x, bv.y, bv.z, bv.w};
#pragma unroll
      for (int i = 0; i < 4; ++i)
#pragma unroll
        for (int j = 0; j < 4; ++j) acc[i][j] = fmaf(a[i], b[j], acc[i][j]);
    }
    __syncthreads();
  }

  const int n0 = bn + tx * 4;
  if ((N & 3) == 0) {
    if (n0 < N) {
      float4 bsv = *(const float4*)&bias[n0];
#pragma unroll
      for (int i = 0; i < 4; ++i) {
        int m = bm + ty * 4 + i;
        float4 v;
        v.x = acc[i][0] + bsv.x;
        v.y = acc[i][1] + bsv.y;
        v.z = acc[i][2] + bsv.z;
        v.w = acc[i][3] + bsv.w;
        *(float4*)&C[(size_t)m * N + n0] = v;
      }
    }
  } else {
#pragma unroll
    for (int i = 0; i < 4; ++i) {
      int m = bm + ty * 4 + i;
#pragma unroll
      for (int j = 0; j < 4; ++j) {
        int n = n0 + j;
        if (n < N) C[(size_t)m * N + n] = acc[i][j] + bias[n];
      }
    }
  }
}

// ---------------- persistent GRU recurrence (one chunk of Tc steps) ----------------
// xp:   [B*Tc, 3U] chunk input projections (incl. input bias), row = b*Tc + (t-t0)
// Rt:   [3U, U] transposed recurrent kernel; brec: [3U]
// hbuf: [2, U, 32] double-buffered transposed hidden state (parity = global t)
// Thread org: b = tid&31, s = (tid>>5)&1 (K-split half), ur = tid>>6 (4 units/block)
__global__ __launch_bounds__(256) void gru_rec(const float* __restrict__ xp,
                                               const float* __restrict__ Rt,
                                               const float* __restrict__ brec,
                                               float* __restrict__ hbuf,
                                               float* __restrict__ out1, int stride1, int rmode1,
                                               float* __restrict__ out2, int stride2, int rmode2,
                                               int U, int act, int vec8,
                                               unsigned* flags, int nblk,
                                               int t0, int tc, int initH) {
  const int tid = threadIdx.x;
  const int b = tid & 31;
  const int s = (tid >> 5) & 1;
  const int ur = tid >> 6;
  const int j = blockIdx.x * 4 + ur;
  const bool own = (j < U);
  const int U32 = U * 32;
  const int U3 = 3 * U;
  __shared__ float red[4][32][3];

  unsigned phase = 1;
  if (initH && own && s == 0) hbuf[j * 32 + b] = 0.f;  // h0 = 0 in buffer 0
  gbar(flags, nblk, phase++);

  const float* rzp = Rt;
  const float* rrp = Rt;
  const float* rhp = Rt;
  if (own) {
    rzp = Rt + (size_t)j * U;
    rrp = Rt + (size_t)(U + j) * U;
    rhp = Rt + (size_t)(2 * U + j) * U;
  }

  for (int tt = 0; tt < tc; ++tt) {
    const int t = t0 + tt;
    const float* hc = hbuf + (t & 1) * U32;
    float* hn = hbuf + ((t + 1) & 1) * U32;
    float za = 0.f, ra = 0.f, ha = 0.f;
    if (own) {
      if (vec8) {
        for (int k0 = s * 4; k0 < U; k0 += 8) {
          float4 wz = *(const float4*)(rzp + k0);
          float4 wr = *(const float4*)(rrp + k0);
          float4 wh = *(const float4*)(rhp + k0);
          const float* hb = hc + k0 * 32 + b;
          float h0 = hb[0], h1 = hb[32], h2 = hb[64], h3 = hb[96];
          za = fmaf(wz.x, h0, fmaf(wz.y, h1, fmaf(wz.z, h2, fmaf(wz.w, h3, za))));
          ra = fmaf(wr.x, h0, fmaf(wr.y, h1, fmaf(wr.z, h2, fmaf(wr.w, h3, ra))));
          ha = fmaf(wh.x, h0, fmaf(wh.y, h1, fmaf(wh.z, h2, fmaf(wh.w, h3, ha))));
        }
      } else {
        for (int k = s; k < U; k += 2) {
          float hv = hc[k * 32 + b];
          za = fmaf(rzp[k], hv, za);
          ra = fmaf(rrp[k], hv, ra);
          ha = fmaf(rhp[k], hv, ha);
        }
      }
    }
    if (own && s == 1) {
      red[ur][b][0] = za;
      red[ur][b][1] = ra;
      red[ur][b][2] = ha;
    }
    __syncthreads();
    if (own && s == 0) {
      za += red[ur][b][0];
      ra += red[ur][b][1];
      ha += red[ur][b][2];
      size_t row_l = (size_t)b * tc + tt;
      const float* xrow = xp + row_l * (size_t)U3;
      float xz = xrow[j], xr = xrow[U + j], xh = xrow[2 * U + j];
      float rz = za + brec[j];
      float rr = ra + brec[U + j];
      float rh = ha + brec[2 * U + j];
      float z = 1.f / (1.f + __expf(-(xz + rz)));
      float r = 1.f / (1.f + __expf(-(xr + rr)));
      float hhp = xh + r * rh;
      float hh = act ? fmaxf(hhp, 0.f) : hhp;
      float hold = hc[j * 32 + b];
      float hnew = z * hold + (1.f - z) * hh;
      hn[j * 32 + b] = hnew;
      size_t row1 = rmode1 ? ((size_t)b * TT + t) : row_l;
      out1[row1 * (size_t)stride1 + j] = hnew;
      if (out2) {
        size_t row2 = rmode2 ? ((size_t)b * TT + t) : row_l;
        out2[row2 * (size_t)stride2 + j] = hnew;
      }
    }
    gbar(flags, nblk, phase++);
  }
}

// ---------------- host launch ----------------
extern "C" void kernel_launch(void* const* d_in, const int* in_sizes, int n_in,
                              void* d_out, int out_size, void* d_ws, size_t ws_size,
                              hipStream_t stream) {
  const float* x = (const float*)d_in[0];
  struct LSpec { int Fi, U, act; };
  const LSpec Ls[6] = {{512, 1024, 1}, {1024, 128, 1}, {128, 23, 0},
                       {151, 256, 1},  {256, 128, 1},  {128, 8, 0}};

  // ---- pick chunk size Tc to fit ws_size ----
  // fixed: flags (192 slots * 1KB) + hbufs + rT
  size_t rt_floats = 0;
  for (int l = 0; l < 6; ++l) rt_floats += (size_t)3 * Ls[l].U * Ls[l].U + 64;
  size_t hb_floats = 0;
  for (int l = 0; l < 6; ++l) hb_floats += (size_t)2 * Ls[l].U * 32 + 64;
  size_t fixed = 192 * 256 * sizeof(unsigned) + (rt_floats + hb_floats) * sizeof(float) + 65536;
  int tcLog2 = 6;
  for (; tcLog2 >= 4; --tcLog2) {
    size_t rc = (size_t)BB << tcLog2;
    size_t perchunk = rc * (3072 + 1024 + 151 + 256 + 128) * sizeof(float) + 8192;
    if (fixed + perchunk <= ws_size) break;
    if (tcLog2 == 4) break;  // smallest supported; proceed regardless
  }
  const int Tc = 1 << tcLog2;
  const int NCk = TT / Tc;
  const size_t RC = (size_t)BB * Tc;

  char* ws = (char*)d_ws;
  size_t off = 0;
  auto alloc = [&](size_t bytes) -> char* {
    char* p = ws + off;
    off += (bytes + 255) & ~(size_t)255;
    return p;
  };

  unsigned* flags = (unsigned*)alloc(192 * 256 * sizeof(unsigned));
  float* hb[6];
  for (int l = 0; l < 6; ++l) hb[l] = (float*)alloc((size_t)2 * Ls[l].U * 32 * sizeof(float));
  float* rT[6];
  for (int l = 0; l < 6; ++l)
    rT[l] = (float*)alloc(((size_t)3 * Ls[l].U * Ls[l].U + 16) * sizeof(float));
  float* xpc = (float*)alloc(RC * 3072 * sizeof(float));  // shared arena, max 3U=3072
  float* y1c = (float*)alloc(RC * 1024 * sizeof(float));
  float* ycc = (float*)alloc(RC * 151 * sizeof(float));
  float* y4c = (float*)alloc(RC * 256 * sizeof(float));
  float* y5c = (float*)alloc(RC * 128 * sizeof(float));

  float* outye = (float*)d_out;
  float* outyd = outye + (size_t)BB * TT * 23;

  hipMemsetAsync(flags, 0, 192 * 256 * sizeof(unsigned), stream);

  // transpose recurrent kernels once per launch
  for (int l = 0; l < 6; ++l) {
    const float* R = (const float*)d_in[2 + 3 * l];
    int U = Ls[l].U, C3 = 3 * U;
    int tot = U * C3;
    hipLaunchKernelGGL(transpose_k, dim3((tot + 255) / 256), dim3(256), 0, stream,
                       R, rT[l], U, C3);
  }

  // per-layer GEMM input descriptors (chunk-local buffers except layer 0 = x)
  const float* Aptr[6] = {x, y1c, ycc, ycc, y4c, y5c};
  const int lda[6] = {512, 1024, 151, 151, 256, 128};
  // per-layer recurrence outputs
  float* O1[6] = {y1c, ycc, outye, y4c, y5c, outyd};
  const int s1[6] = {1024, 151, 23, 256, 128, 8};
  const int m1[6] = {0, 0, 1, 0, 0, 1};  // 0=chunk-local rows, 1=global rows
  float* O2[6] = {nullptr, nullptr, ycc + 128, nullptr, nullptr, nullptr};
  const int s2[6] = {0, 0, 151, 0, 0, 0};
  const int m2[6] = {0, 0, 0, 0, 0, 0};

  for (int c = 0; c < NCk; ++c) {
    const int t0 = c * Tc;
    for (int l = 0; l < 6; ++l) {
      const int U = Ls[l].U, Fi = Ls[l].Fi, N = 3 * U;
      const float* K = (const float*)d_in[1 + 3 * l];
      const float* bias = (const float*)d_in[3 + 3 * l];

      dim3 gg((N + 63) / 64, (unsigned)(RC / 64));
      hipLaunchKernelGGL(gemm_bias, gg, dim3(256), 0, stream,
                         Aptr[l], lda[l], K, bias, xpc, (int)RC, N, Fi,
                         (l == 0) ? t0 : -1, tcLog2);

      const int nblk = (U + 3) / 4;
      unsigned* fl = flags + (size_t)(c * 6 + l) * 256;
      hipLaunchKernelGGL(gru_rec, dim3(nblk), dim3(256), 0, stream,
                         xpc, rT[l], bias + N, hb[l],
                         O1[l], s1[l], m1[l], O2[l], s2[l], m2[l],
                         U, Ls[l].act, (U % 8) == 0 ? 1 : 0,
                         fl, nblk, t0, Tc, (c == 0) ? 1 : 0);
    }
  }
}

// Round 3
// 41572.415 us; speedup vs baseline: 1.4694x; 1.4694x over previous
//
#include <hip/hip_runtime.h>
#include <cstdint>
#include <cstddef>

#define BB 32
#define TT 512

// ---------------- flag-based grid barrier, LLC-coherent, no cache nukes ------------
// Arrival: RELEASE store (drains vmcnt so sc1 h-stores are LLC-visible).
// Wait: RELAXED agent-scope polls (sc1 loads bypass L1/L2 -> no invalidate needed,
// so read-only weights stay hot in L1/L2 across all timesteps).
__device__ __forceinline__ void gbar(unsigned* flags, int nblk, unsigned phase) {
  __syncthreads();
  if (threadIdx.x == 0)
    __hip_atomic_store(&flags[blockIdx.x], phase, __ATOMIC_RELEASE, __HIP_MEMORY_SCOPE_AGENT);
  for (;;) {
    int ok = 1;
    for (int i = threadIdx.x; i < nblk; i += 256)
      ok &= (__hip_atomic_load(&flags[i], __ATOMIC_RELAXED, __HIP_MEMORY_SCOPE_AGENT) >= phase) ? 1 : 0;
    if (__syncthreads_count(ok) == 256) break;
    __builtin_amdgcn_s_sleep(1);
  }
}

// ---------------- transpose R[U,3U] -> Rt[3U, Upad] (pad k with zeros) -------------
__global__ __launch_bounds__(256) void transpose_k(const float* __restrict__ in,
                                                   float* __restrict__ outp,
                                                   int U, int Upad) {
  int idx = blockIdx.x * 256 + threadIdx.x;
  int total = 3 * U * Upad;
  if (idx < total) {
    int c = idx / Upad;      // output gate-column 0..3U-1
    int k = idx % Upad;      // k index (padded)
    outp[idx] = (k < U) ? in[(size_t)k * (3 * U) + c] : 0.f;
  }
}

// ---------------- fp32 tiled GEMM: C[M,N] = A[M,K] @ W[K,N] + bias[N] ----------------
__global__ __launch_bounds__(256) void gemm_bias(const float* __restrict__ A, int lda,
                                                 const float* __restrict__ W,
                                                 const float* __restrict__ bias,
                                                 float* __restrict__ C,
                                                 int M, int N, int K,
                                                 int t0, int tcLog2) {
  __shared__ float As[16][68];
  __shared__ float Ws[16][68];
  const int bm = blockIdx.y * 64;
  const int bn = blockIdx.x * 64;
  const int tx = threadIdx.x & 15;
  const int ty = threadIdx.x >> 4;
  const int tcMask = (1 << tcLog2) - 1;
  float acc[4][4] = {};

  for (int k0 = 0; k0 < K; k0 += 16) {
    for (int i = threadIdx.x; i < 64 * 16; i += 256) {
      int r = i >> 4, c = i & 15;
      int kk = k0 + c;
      int rg = bm + r;
      size_t arow;
      if (t0 >= 0)
        arow = ((size_t)(rg >> tcLog2) << 9) + t0 + (rg & tcMask);
      else
        arow = (size_t)rg;
      As[c][r] = (kk < K) ? A[arow * lda + kk] : 0.f;
    }
    for (int i = threadIdx.x; i < 16 * 64; i += 256) {
      int r = i >> 6, c = i & 63;
      int kk = k0 + r, nn = bn + c;
      Ws[r][c] = (kk < K && nn < N) ? W[(size_t)kk * N + nn] : 0.f;
    }
    __syncthreads();
#pragma unroll
    for (int kk = 0; kk < 16; ++kk) {
      float4 av = *(const float4*)&As[kk][ty * 4];
      float4 bv = *(const float4*)&Ws[kk][tx * 4];
      float a[4] = {av.x, av.y, av.z, av.w};
      float b[4] = {bv.x, bv.y, bv.z, bv.w};
#pragma unroll
      for (int i = 0; i < 4; ++i)
#pragma unroll
        for (int j = 0; j < 4; ++j) acc[i][j] = fmaf(a[i], b[j], acc[i][j]);
    }
    __syncthreads();
  }

  const int n0 = bn + tx * 4;
  if ((N & 3) == 0) {
    if (n0 < N) {
      float4 bsv = *(const float4*)&bias[n0];
#pragma unroll
      for (int i = 0; i < 4; ++i) {
        int m = bm + ty * 4 + i;
        float4 v;
        v.x = acc[i][0] + bsv.x;
        v.y = acc[i][1] + bsv.y;
        v.z = acc[i][2] + bsv.z;
        v.w = acc[i][3] + bsv.w;
        *(float4*)&C[(size_t)m * N + n0] = v;
      }
    }
  } else {
#pragma unroll
    for (int i = 0; i < 4; ++i) {
      int m = bm + ty * 4 + i;
#pragma unroll
      for (int j = 0; j < 4; ++j) {
        int n = n0 + j;
        if (n < N) C[(size_t)m * N + n] = acc[i][j] + bias[n];
      }
    }
  }
}

// ---------------- persistent GRU recurrence (one chunk of tc steps) ----------------
// xp:   [B*tc, 3U] input projections (incl. input bias), row = b*tc + tt
// Rt:   [3U, Upad] transposed recurrent kernel (k-padded with zeros)
// brec: [3U]
// hbuf: [2, Upad, 32] double-buffered h, [k][b] layout; exchanged via sc1 atomics.
// Thread org: b = tid&31, sid = (tid>>5)&(ks-1) (K split), ur = tid>>(5+ksLog2).
__global__ __launch_bounds__(256, 2) void gru_rec(const float* __restrict__ xp,
                                                  const float* __restrict__ Rt,
                                                  const float* __restrict__ brec,
                                                  float* __restrict__ hbuf,
                                                  float* __restrict__ out1, int stride1, int rmode1,
                                                  float* __restrict__ out2, int stride2, int rmode2,
                                                  int U, int Upad, int act, int ksLog2,
                                                  unsigned* flags, int nblk,
                                                  int t0, int tc, int initH) {
  const int tid = threadIdx.x;
  const int b = tid & 31;
  const int ks = 1 << ksLog2;
  const int sid = (tid >> 5) & (ks - 1);
  const int ur = tid >> (5 + ksLog2);
  const int jpb = 8 >> ksLog2;                   // j's per block
  const int j = blockIdx.x * jpb + ur;
  const bool own = (j < U);
  const int U32 = Upad * 32;
  const int U3 = 3 * U;
  const int kstep = 4 << ksLog2;
  __shared__ float red[4][3][32][3];             // [ur][sid-1][b][gate]

  unsigned phase = 1;
  if (initH) {  // zero both parities (incl. pad rows) via sc1 stores
    for (int i = tid; i < 2 * U32; i += 256)
      __hip_atomic_store(&hbuf[i], 0.f, __ATOMIC_RELAXED, __HIP_MEMORY_SCOPE_AGENT);
  }
  gbar(flags, nblk, phase++);

  const float* rzp = Rt;
  const float* rrp = Rt;
  const float* rhp = Rt;
  float bz = 0.f, br = 0.f, bh = 0.f, hprev = 0.f;
  if (own) {
    rzp = Rt + (size_t)j * Upad;
    rrp = Rt + (size_t)(U + j) * Upad;
    rhp = Rt + (size_t)(2 * U + j) * Upad;
    if (sid == 0) {
      bz = brec[j]; br = brec[U + j]; bh = brec[2 * U + j];
      hprev = __hip_atomic_load(&hbuf[(t0 & 1) * U32 + j * 32 + b],
                                __ATOMIC_RELAXED, __HIP_MEMORY_SCOPE_AGENT);
    }
  }

  for (int tt = 0; tt < tc; ++tt) {
    const int t = t0 + tt;
    float* hc = hbuf + (t & 1) * U32;
    float* hn = hbuf + ((t + 1) & 1) * U32;
    float za = 0.f, ra = 0.f, ha = 0.f;
    if (own) {
      for (int k0 = sid * 4; k0 < Upad; k0 += kstep) {
        float4 wz = *(const float4*)(rzp + k0);
        float4 wr = *(const float4*)(rrp + k0);
        float4 wh = *(const float4*)(rhp + k0);
        float* hb = hc + k0 * 32 + b;
        float h0 = __hip_atomic_load(hb +  0, __ATOMIC_RELAXED, __HIP_MEMORY_SCOPE_AGENT);
        float h1 = __hip_atomic_load(hb + 32, __ATOMIC_RELAXED, __HIP_MEMORY_SCOPE_AGENT);
        float h2 = __hip_atomic_load(hb + 64, __ATOMIC_RELAXED, __HIP_MEMORY_SCOPE_AGENT);
        float h3 = __hip_atomic_load(hb + 96, __ATOMIC_RELAXED, __HIP_MEMORY_SCOPE_AGENT);
        za = fmaf(wz.x, h0, fmaf(wz.y, h1, fmaf(wz.z, h2, fmaf(wz.w, h3, za))));
        ra = fmaf(wr.x, h0, fmaf(wr.y, h1, fmaf(wr.z, h2, fmaf(wr.w, h3, ra))));
        ha = fmaf(wh.x, h0, fmaf(wh.y, h1, fmaf(wh.z, h2, fmaf(wh.w, h3, ha))));
      }
    }
    if (own && sid > 0) {
      red[ur][sid - 1][b][0] = za;
      red[ur][sid - 1][b][1] = ra;
      red[ur][sid - 1][b][2] = ha;
    }
    __syncthreads();
    if (own && sid == 0) {
      for (int ss = 0; ss < ks - 1; ++ss) {
        za += red[ur][ss][b][0];
        ra += red[ur][ss][b][1];
        ha += red[ur][ss][b][2];
      }
      size_t row_l = (size_t)b * tc + tt;
      const float* xrow = xp + row_l * (size_t)U3;
      float xz = xrow[j], xr = xrow[U + j], xh = xrow[2 * U + j];
      float z = 1.f / (1.f + __expf(-(xz + za + bz)));
      float r = 1.f / (1.f + __expf(-(xr + ra + br)));
      float hhp = xh + r * (ha + bh);
      float hh = act ? fmaxf(hhp, 0.f) : hhp;
      float hnew = z * hprev + (1.f - z) * hh;
      hprev = hnew;
      __hip_atomic_store(&hn[j * 32 + b], hnew, __ATOMIC_RELAXED, __HIP_MEMORY_SCOPE_AGENT);
      size_t row1 = rmode1 ? ((size_t)b * TT + t) : row_l;
      out1[row1 * (size_t)stride1 + j] = hnew;
      if (out2) {
        size_t row2 = rmode2 ? ((size_t)b * TT + t) : row_l;
        out2[row2 * (size_t)stride2 + j] = hnew;
      }
    }
    gbar(flags, nblk, phase++);
  }
}

// ---------------- host launch ----------------
extern "C" void kernel_launch(void* const* d_in, const int* in_sizes, int n_in,
                              void* d_out, int out_size, void* d_ws, size_t ws_size,
                              hipStream_t stream) {
  const float* x = (const float*)d_in[0];
  struct LSpec { int Fi, U, Upad, act, ksLog2; };
  const LSpec Ls[6] = {{512, 1024, 1024, 1, 2}, {1024, 128, 128, 1, 1},
                       {128, 23, 24, 0, 1},     {151, 256, 256, 1, 2},
                       {256, 128, 128, 1, 1},   {128, 8, 8, 0, 1}};

  int tcLog2 = 6;
  {
    size_t rt_floats = 0, hb_floats = 0;
    for (int l = 0; l < 6; ++l) rt_floats += (size_t)3 * Ls[l].U * Ls[l].Upad + 64;
    for (int l = 0; l < 6; ++l) hb_floats += (size_t)2 * Ls[l].Upad * 32 + 64;
    size_t fixed = 48 * 512 * sizeof(unsigned) + (rt_floats + hb_floats) * sizeof(float) + 65536;
    for (; tcLog2 >= 4; --tcLog2) {
      size_t rc = (size_t)BB << tcLog2;
      size_t perchunk = rc * (3072 + 1024 + 151 + 256 + 128) * sizeof(float) + 8192;
      if (fixed + perchunk <= ws_size) break;
      if (tcLog2 == 4) break;
    }
  }
  const int Tc = 1 << tcLog2;
  const int NCk = TT / Tc;
  const size_t RC = (size_t)BB * Tc;

  char* ws = (char*)d_ws;
  size_t off = 0;
  auto alloc = [&](size_t bytes) -> char* {
    char* p = ws + off;
    off += (bytes + 255) & ~(size_t)255;
    return p;
  };

  unsigned* flags = (unsigned*)alloc(48 * 512 * sizeof(unsigned));
  float* hb[6];
  for (int l = 0; l < 6; ++l) hb[l] = (float*)alloc((size_t)2 * Ls[l].Upad * 32 * sizeof(float));
  float* rT[6];
  for (int l = 0; l < 6; ++l)
    rT[l] = (float*)alloc(((size_t)3 * Ls[l].U * Ls[l].Upad + 16) * sizeof(float));
  float* xpc = (float*)alloc(RC * 3072 * sizeof(float));
  float* y1c = (float*)alloc(RC * 1024 * sizeof(float));
  float* ycc = (float*)alloc(RC * 151 * sizeof(float));
  float* y4c = (float*)alloc(RC * 256 * sizeof(float));
  float* y5c = (float*)alloc(RC * 128 * sizeof(float));

  float* outye = (float*)d_out;
  float* outyd = outye + (size_t)BB * TT * 23;

  hipMemsetAsync(flags, 0, 48 * 512 * sizeof(unsigned), stream);

  for (int l = 0; l < 6; ++l) {
    const float* R = (const float*)d_in[2 + 3 * l];
    int tot = 3 * Ls[l].U * Ls[l].Upad;
    hipLaunchKernelGGL(transpose_k, dim3((tot + 255) / 256), dim3(256), 0, stream,
                       R, rT[l], Ls[l].U, Ls[l].Upad);
  }

  const float* Aptr[6] = {x, y1c, ycc, ycc, y4c, y5c};
  const int lda[6] = {512, 1024, 151, 151, 256, 128};
  float* O1[6] = {y1c, ycc, outye, y4c, y5c, outyd};
  const int s1[6] = {1024, 151, 23, 256, 128, 8};
  const int m1[6] = {0, 0, 1, 0, 0, 1};
  float* O2[6] = {nullptr, nullptr, ycc + 128, nullptr, nullptr, nullptr};
  const int s2[6] = {0, 0, 151, 0, 0, 0};
  const int m2[6] = {0, 0, 0, 0, 0, 0};

  for (int c = 0; c < NCk; ++c) {
    const int t0 = c * Tc;
    for (int l = 0; l < 6; ++l) {
      const int U = Ls[l].U, Fi = Ls[l].Fi, N = 3 * U;
      const float* K = (const float*)d_in[1 + 3 * l];
      const float* bias = (const float*)d_in[3 + 3 * l];

      dim3 gg((N + 63) / 64, (unsigned)(RC / 64));
      hipLaunchKernelGGL(gemm_bias, gg, dim3(256), 0, stream,
                         Aptr[l], lda[l], K, bias, xpc, (int)RC, N, Fi,
                         (l == 0) ? t0 : -1, tcLog2);

      const int jpb = 8 >> Ls[l].ksLog2;
      const int nblk = (U + jpb - 1) / jpb;
      unsigned* fl = flags + (size_t)(c * 6 + l) * 512;
      hipLaunchKernelGGL(gru_rec, dim3(nblk), dim3(256), 0, stream,
                         xpc, rT[l], bias + N, hb[l],
                         O1[l], s1[l], m1[l], O2[l], s2[l], m2[l],
                         U, Ls[l].Upad, Ls[l].act, Ls[l].ksLog2,
                         fl, nblk, t0, Tc, (c == 0) ? 1 : 0);
    }
  }
}

// Round 4
// 39798.450 us; speedup vs baseline: 1.5349x; 1.0446x over previous
//
#include <hip/hip_runtime.h>
#include <hip/hip_bf16.h>
#include <cstdint>
#include <cstddef>

#define BB 32
#define TT 512

typedef short s8v __attribute__((ext_vector_type(8)));
typedef short s4v __attribute__((ext_vector_type(4)));
typedef float f4v __attribute__((ext_vector_type(4)));
typedef unsigned long long u64;
typedef unsigned short u16;
typedef unsigned int u32;

__device__ __forceinline__ short f2b(float x) {
  __hip_bfloat16 h = __float2bfloat16(x);
  return *reinterpret_cast<short*>(&h);
}
__device__ __forceinline__ float b2f(u16 x) {
  __hip_bfloat16 h = *reinterpret_cast<__hip_bfloat16*>(&x);
  return __bfloat162float(h);
}
__device__ __forceinline__ float sigm(float x) { return 1.f / (1.f + __expf(-x)); }

// ---------------- grid barrier (flag array, LLC-coherent, no cache nukes) ----------
__device__ __forceinline__ void gbar(unsigned* flags, int nblk, unsigned phase) {
  __syncthreads();
  if (threadIdx.x == 0)
    __hip_atomic_store(&flags[blockIdx.x], phase, __ATOMIC_RELEASE, __HIP_MEMORY_SCOPE_AGENT);
  for (;;) {
    int ok = 1;
    for (int i = threadIdx.x; i < nblk; i += blockDim.x)
      ok &= (__hip_atomic_load(&flags[i], __ATOMIC_RELAXED, __HIP_MEMORY_SCOPE_AGENT) >= phase) ? 1 : 0;
    if (__syncthreads_count(ok) == (int)blockDim.x) break;
    __builtin_amdgcn_s_sleep(1);
  }
}

// ---------------- x -> bf16 cast ----------------
__global__ __launch_bounds__(256) void cast_bf16(const float* __restrict__ in,
                                                 u16* __restrict__ outp, int n4) {
  int i = blockIdx.x * 256 + threadIdx.x;
  if (i < n4) {
    float4 v = *(const float4*)(in + (size_t)i * 4);
    u16 o[4] = {(u16)f2b(v.x), (u16)f2b(v.y), (u16)f2b(v.z), (u16)f2b(v.w)};
    *(u64*)(outp + (size_t)i * 4) = *(const u64*)o;
  }
}

// ---------------- weight -> MFMA B-fragment order (bf16) ----------------
// src [Ksrc, N] fp32 row-major. dst frags [fid][lane][8] bf16.
// recmode: fid = (g*JT + jt)*Ks + ks, n = g*U + jt*16 + (lane&15), valid if jt*16+l15 < U
// gemm:    fid = nt*Ks + ks,          n = nt*16 + (lane&15),       valid if n < N
__global__ __launch_bounds__(256) void prep_frags(const float* __restrict__ src,
                                                  u16* __restrict__ dst,
                                                  int N, int Ksrc, int Ks,
                                                  int JT, int U, int recmode, int total_fid) {
  int t = blockIdx.x * 256 + threadIdx.x;
  int lane = t & 63, fid = t >> 6;
  if (fid >= total_fid) return;
  int l15 = lane & 15, quad = lane >> 4;
  int ks = fid % Ks;
  int n, valid_n;
  if (recmode) {
    int rest = fid / Ks;
    int jt = rest % JT;
    int g = rest / JT;
    int jj = jt * 16 + l15;
    n = g * U + jj;
    valid_n = (jj < U) ? 1 : 0;
  } else {
    int nt = fid / Ks;
    n = nt * 16 + l15;
    valid_n = (n < N) ? 1 : 0;
  }
  u16* o = dst + ((size_t)fid * 64 + lane) * 8;
#pragma unroll
  for (int j = 0; j < 8; ++j) {
    int k = ks * 32 + quad * 8 + j;
    float v = (valid_n && k < Ksrc) ? src[(size_t)k * N + n] : 0.f;
    o[j] = (u16)f2b(v);
  }
}

// ---------------- MFMA GEMM: C[M,N] = A[M,Kact]_bf16 @ W + bias ----------------
// A staged to LDS (padded rows); B from frag-order global. One M-tile (16 rows)/block,
// 4 waves x 4 n-tiles each. If t0>=0, A rows are chunk-mapped into x[B,T,F].
__global__ __launch_bounds__(256) void gemm_mfma(const u16* __restrict__ A, int strideA, int Kact,
                                                 const u16* __restrict__ Bf,
                                                 const float* __restrict__ bias,
                                                 float* __restrict__ C,
                                                 int N, int Ntiles, int Ks,
                                                 int t0, int tcLog2) {
  __shared__ char sha[16 * 2056];
  const int tid = threadIdx.x;
  const int lane = tid & 63, l15 = lane & 15, quad = lane >> 4, w = tid >> 6;
  const int KS4 = Ks * 8;          // 8B units per LDS row
  const int rowB = Ks * 64 + 8;    // LDS row bytes (pad 8)
  const int bm = blockIdx.y * 16;

  for (int i = tid; i < 16 * KS4; i += 256) {
    int r = i / KS4, u = i - r * KS4;
    u64 v = 0;
    if (u * 4 < Kact) {
      int rl = bm + r;
      size_t grow;
      if (t0 >= 0) {
        int tcm = (1 << tcLog2) - 1;
        grow = (((size_t)(rl >> tcLog2)) << 9) + t0 + (rl & tcm);
      } else {
        grow = (size_t)rl;
      }
      v = *((const u64*)(A + grow * (size_t)strideA) + u);
    }
    *(u64*)(sha + r * rowB + u * 8) = v;
  }
  __syncthreads();

  f4v acc[4];
  f4v z4 = {0.f, 0.f, 0.f, 0.f};
#pragma unroll
  for (int q = 0; q < 4; ++q) acc[q] = z4;

  const int ntb = blockIdx.x * 16 + w * 4;
  for (int ks = 0; ks < Ks; ++ks) {
    int off = l15 * rowB + ks * 64 + quad * 16;
    s4v lo = *(const s4v*)(sha + off);
    s4v hi = *(const s4v*)(sha + off + 8);
    s8v a = __builtin_shufflevector(lo, hi, 0, 1, 2, 3, 4, 5, 6, 7);
#pragma unroll
    for (int q = 0; q < 4; ++q) {
      int nt = ntb + q;
      if (nt < Ntiles) {
        s8v b = *(const s8v*)(Bf + (((size_t)nt * Ks + ks) * 64 + lane) * 8);
        acc[q] = __builtin_amdgcn_mfma_f32_16x16x32_bf16(a, b, acc[q], 0, 0, 0);
      }
    }
  }
#pragma unroll
  for (int q = 0; q < 4; ++q) {
    int nt = ntb + q;
    if (nt >= Ntiles) continue;
    int col = nt * 16 + l15;
    if (col < N) {
      float bv = bias[col];
#pragma unroll
      for (int r = 0; r < 4; ++r) {
        int rowl = bm + quad * 4 + r;
        C[(size_t)rowl * N + col] = acc[q][r] + bv;
      }
    }
  }
}

// ---------------- multi-block MFMA GRU recurrence (L1: 64x1-wave, L4: 8x2-wave) ------
// hbuf: [2][32][Kpad] bf16 global, exchanged via sc1. LDS: h staged per step.
// Wave owns 16 units; lane l: j = jt*16 + (l&15); hprev fp32 in regs.
__global__ __launch_bounds__(128) void rec_multi(const float* __restrict__ xp,
                                                 const u16* __restrict__ Bf,
                                                 const float* __restrict__ brec,
                                                 u16* __restrict__ hbuf,
                                                 u16* __restrict__ outb, int strideO,
                                                 int U, int Kpad, int Ks, int JT,
                                                 int act, int swz, int ushift,
                                                 unsigned* flags, int nblk,
                                                 int t0, int tc, int initH) {
  __shared__ char shm[65536];
  const int tid = threadIdx.x;
  const int lane = tid & 63, l15 = lane & 15, quad = lane >> 4;
  const int w = tid >> 6;
  const int NW = blockDim.x >> 6;
  const int jt = blockIdx.x * NW + w;
  const int j = jt * 16 + l15;
  const int S3U = 3 * U;
  const int HP = 32 * Kpad;        // elems per parity
  const int rowB = Kpad * 2 + 8;   // pad-mode LDS row bytes

  unsigned phase = 1;
  if (initH) {
    u32* hz = (u32*)hbuf;
    int tot = 32 * Kpad;  // u32 words over both parities
    for (int i = tid + blockIdx.x * blockDim.x; i < tot; i += gridDim.x * blockDim.x)
      __hip_atomic_store(hz + i, 0u, __ATOMIC_RELAXED, __HIP_MEMORY_SCOPE_AGENT);
  }
  gbar(flags, nblk, phase++);

  const float bz = brec[j], brr = brec[U + j], bh = brec[2 * U + j];
  float hprev[8];
  {
    const u32* hp = (const u32*)(hbuf + (size_t)(t0 & 1) * HP);
#pragma unroll
    for (int Mt = 0; Mt < 2; ++Mt)
#pragma unroll
      for (int r = 0; r < 4; ++r) {
        int b = Mt * 16 + quad * 4 + r;
        u32 wd = __hip_atomic_load((u32*)hp + ((b * Kpad + (j & ~1)) >> 1),
                                   __ATOMIC_RELAXED, __HIP_MEMORY_SCOPE_AGENT);
        hprev[Mt * 4 + r] = b2f((j & 1) ? (u16)(wd >> 16) : (u16)(wd & 0xffff));
      }
  }

  for (int tt = 0; tt < tc; ++tt) {
    const int t = t0 + tt;
    // prefetch xp (independent of h)
    float xv[3][8];
#pragma unroll
    for (int Mt = 0; Mt < 2; ++Mt)
#pragma unroll
      for (int r = 0; r < 4; ++r) {
        int b = Mt * 16 + quad * 4 + r;
        const float* xr_ = xp + ((size_t)b * tc + tt) * S3U;
        xv[0][Mt * 4 + r] = xr_[j];
        xv[1][Mt * 4 + r] = xr_[U + j];
        xv[2][Mt * 4 + r] = xr_[2 * U + j];
      }
    // stage h into LDS
    const u64* hsrc = (const u64*)(hbuf + (size_t)(t & 1) * HP);
    const int nunits = Kpad * 8;
    for (int i = tid; i < nunits; i += blockDim.x) {
      int m = i >> ushift;
      int u = i - (m << ushift);
      u64 v = __hip_atomic_load((u64*)hsrc + i, __ATOMIC_RELAXED, __HIP_MEMORY_SCOPE_AGENT);
      int off;
      if (swz) off = m * 2048 + ((((u >> 1) ^ (m & 15)) << 4) | ((u & 1) << 3));
      else off = m * rowB + (u << 3);
      *(u64*)(shm + off) = v;
    }
    __syncthreads();
    // MFMA
    f4v acc[3][2];
    f4v z4 = {0.f, 0.f, 0.f, 0.f};
#pragma unroll
    for (int g = 0; g < 3; ++g) { acc[g][0] = z4; acc[g][1] = z4; }
#pragma unroll
    for (int Mt = 0; Mt < 2; ++Mt) {
      int m = Mt * 16 + l15;
      for (int ks = 0; ks < Ks; ++ks) {
        int off;
        if (swz) off = m * 2048 + (((((ks << 2) + quad) ^ (m & 15))) << 4);
        else off = m * rowB + (ks << 6) + (quad << 4);
        s4v lo = *(const s4v*)(shm + off);
        s4v hi = *(const s4v*)(shm + off + 8);
        s8v a = __builtin_shufflevector(lo, hi, 0, 1, 2, 3, 4, 5, 6, 7);
#pragma unroll
        for (int g = 0; g < 3; ++g) {
          s8v b = *(const s8v*)(Bf + (((size_t)(g * JT + jt) * Ks + ks) * 64 + lane) * 8);
          acc[g][Mt] = __builtin_amdgcn_mfma_f32_16x16x32_bf16(a, b, acc[g][Mt], 0, 0, 0);
        }
      }
    }
    // gates + publish
    u16* hdst = hbuf + (size_t)((t + 1) & 1) * HP;
#pragma unroll
    for (int Mt = 0; Mt < 2; ++Mt)
#pragma unroll
      for (int r = 0; r < 4; ++r) {
        int b = Mt * 16 + quad * 4 + r;
        size_t row = (size_t)b * tc + tt;
        float z = sigm(xv[0][Mt * 4 + r] + acc[0][Mt][r] + bz);
        float rr = sigm(xv[1][Mt * 4 + r] + acc[1][Mt][r] + brr);
        float hh = xv[2][Mt * 4 + r] + rr * (acc[2][Mt][r] + bh);
        if (act) hh = fmaxf(hh, 0.f);
        float hnew = z * hprev[Mt * 4 + r] + (1.f - z) * hh;
        hprev[Mt * 4 + r] = hnew;
        float part = __shfl_xor(hnew, 1, 64);
        if ((l15 & 1) == 0) {
          u32 wd = (u32)(u16)f2b(hnew) | ((u32)(u16)f2b(part) << 16);
          __hip_atomic_store((u32*)hdst + ((b * Kpad + j) >> 1), wd,
                             __ATOMIC_RELAXED, __HIP_MEMORY_SCOPE_AGENT);
          *((u32*)outb + ((row * strideO + j) >> 1)) = wd;
        }
      }
    gbar(flags, nblk, phase++);
  }
}

// ---------------- single-block MFMA GRU recurrence (L2,L3,L5,L6) ----------------
// h double-buffered in LDS (pad-mode rows); persists across chunks via hsave global.
__global__ __launch_bounds__(512) void rec_single(const float* __restrict__ xp,
                                                  const u16* __restrict__ Bf,
                                                  const float* __restrict__ brec,
                                                  u16* __restrict__ hsave,
                                                  u16* __restrict__ outb, int strideO,
                                                  float* __restrict__ outf, int strideF,
                                                  int U, int Kpad, int Ks, int JT,
                                                  int act, int t0, int tc, int initH) {
  __shared__ char shs[16896];
  const int tid = threadIdx.x;
  const int lane = tid & 63, l15 = lane & 15, quad = lane >> 4;
  const int w = tid >> 6;
  const int jt = w;
  const int j = jt * 16 + l15;
  const bool jv = (j < U);
  const int S3U = 3 * U;
  const int rowB = Kpad * 2 + 8;
  const int HB = 32 * rowB;
  const int p0 = t0 & 1;

  // zero both parities (covers k-pads), then restore if not first chunk
  for (int i = tid; i < (2 * HB) >> 2; i += blockDim.x) ((u32*)shs)[i] = 0;
  __syncthreads();
  if (!initH) {
    const int upr = Kpad >> 2;
    for (int i = tid; i < Kpad * 8; i += blockDim.x) {
      int m = i / upr, u = i - m * upr;
      u64 v = *((const u64*)hsave + i);
      *(u64*)(shs + p0 * HB + m * rowB + u * 8) = v;
    }
  }
  __syncthreads();

  const float bz = jv ? brec[j] : 0.f;
  const float brr = jv ? brec[U + j] : 0.f;
  const float bh = jv ? brec[2 * U + j] : 0.f;
  float hprev[8];
#pragma unroll
  for (int Mt = 0; Mt < 2; ++Mt)
#pragma unroll
    for (int r = 0; r < 4; ++r) {
      int b = Mt * 16 + quad * 4 + r;
      hprev[Mt * 4 + r] = jv ? b2f(*(const u16*)(shs + p0 * HB + b * rowB + j * 2)) : 0.f;
    }

  for (int tt = 0; tt < tc; ++tt) {
    const int p = (t0 + tt) & 1;
    float xv[3][8];
#pragma unroll
    for (int Mt = 0; Mt < 2; ++Mt)
#pragma unroll
      for (int r = 0; r < 4; ++r) {
        int b = Mt * 16 + quad * 4 + r;
        const float* xr_ = xp + ((size_t)b * tc + tt) * S3U;
        xv[0][Mt * 4 + r] = jv ? xr_[j] : 0.f;
        xv[1][Mt * 4 + r] = jv ? xr_[U + j] : 0.f;
        xv[2][Mt * 4 + r] = jv ? xr_[2 * U + j] : 0.f;
      }
    f4v acc[3][2];
    f4v z4 = {0.f, 0.f, 0.f, 0.f};
#pragma unroll
    for (int g = 0; g < 3; ++g) { acc[g][0] = z4; acc[g][1] = z4; }
#pragma unroll
    for (int Mt = 0; Mt < 2; ++Mt) {
      int m = Mt * 16 + l15;
      for (int ks = 0; ks < Ks; ++ks) {
        int off = p * HB + m * rowB + (ks << 6) + (quad << 4);
        s4v lo = *(const s4v*)(shs + off);
        s4v hi = *(const s4v*)(shs + off + 8);
        s8v a = __builtin_shufflevector(lo, hi, 0, 1, 2, 3, 4, 5, 6, 7);
#pragma unroll
        for (int g = 0; g < 3; ++g) {
          s8v b = *(const s8v*)(Bf + (((size_t)(g * JT + jt) * Ks + ks) * 64 + lane) * 8);
          acc[g][Mt] = __builtin_amdgcn_mfma_f32_16x16x32_bf16(a, b, acc[g][Mt], 0, 0, 0);
        }
      }
    }
#pragma unroll
    for (int Mt = 0; Mt < 2; ++Mt)
#pragma unroll
      for (int r = 0; r < 4; ++r) {
        int b = Mt * 16 + quad * 4 + r;
        size_t row = (size_t)b * tc + tt;
        float z = sigm(xv[0][Mt * 4 + r] + acc[0][Mt][r] + bz);
        float rr = sigm(xv[1][Mt * 4 + r] + acc[1][Mt][r] + brr);
        float hh = xv[2][Mt * 4 + r] + rr * (acc[2][Mt][r] + bh);
        if (act) hh = fmaxf(hh, 0.f);
        float hnew = z * hprev[Mt * 4 + r] + (1.f - z) * hh;
        hprev[Mt * 4 + r] = hnew;
        if (jv) *(u16*)(shs + (p ^ 1) * HB + b * rowB + j * 2) = (u16)f2b(hnew);
        float part = __shfl_xor(hnew, 1, 64);
        if (outb && jv && (l15 & 1) == 0) {
          float hi_v = ((j + 1) < U) ? part : 0.f;
          u32 wd = (u32)(u16)f2b(hnew) | ((u32)(u16)f2b(hi_v) << 16);
          *((u32*)outb + ((row * strideO + j) >> 1)) = wd;
        }
        if (outf && jv) outf[((size_t)b * TT + t0 + tt) * strideF + j] = hnew;
      }
    __syncthreads();
  }
  // save final parity for next chunk
  {
    const int pf = (t0 + tc) & 1;
    const int upr = Kpad >> 2;
    for (int i = tid; i < Kpad * 8; i += blockDim.x) {
      int m = i / upr, u = i - m * upr;
      *((u64*)hsave + i) = *(const u64*)(shs + pf * HB + m * rowB + u * 8);
    }
  }
}

// ---------------- host launch ----------------
extern "C" void kernel_launch(void* const* d_in, const int* in_sizes, int n_in,
                              void* d_out, int out_size, void* d_ws, size_t ws_size,
                              hipStream_t stream) {
  const float* x = (const float*)d_in[0];
  struct LSpec {
    int Fi, U, act;
    int Kpad, KsR, JT;     // recurrence
    int N, NtG, KsG, KactG; // gemm (N = 3U)
  };
  const LSpec Ls[6] = {
      {512, 1024, 1, 1024, 32, 64, 3072, 192, 16, 512},
      {1024, 128, 1, 128, 4, 8, 384, 24, 32, 1024},
      {128, 23, 0, 32, 1, 2, 69, 5, 4, 128},
      {151, 256, 1, 256, 8, 16, 768, 48, 5, 152},
      {256, 128, 1, 128, 4, 8, 384, 24, 8, 256},
      {128, 8, 0, 32, 1, 1, 24, 2, 4, 128}};

  // ---- sizes (fixed part) ----
  size_t recB_elems[6], gemB_elems[6];
  size_t fixed = 0;
  for (int l = 0; l < 6; ++l) {
    recB_elems[l] = (size_t)3 * Ls[l].JT * Ls[l].KsR * 512;
    gemB_elems[l] = (size_t)Ls[l].NtG * Ls[l].KsG * 512;
    fixed += (recB_elems[l] + gemB_elems[l]) * 2 + 512;
  }
  fixed += 16 * 64 * 4 + 4096;                       // flags
  fixed += (size_t)(2 * 32 * 1024 + 2 * 32 * 256) * 2 + 1024;  // hbuf L1,L4
  fixed += (size_t)32 * (128 + 32 + 128 + 32) * 2 + 1024;      // hsaves
  fixed += (size_t)16384 * 512 * 2 + 256;            // x_bf16
  int tcLog2 = 6;
  for (; tcLog2 >= 4; --tcLog2) {
    size_t rc = (size_t)BB << tcLog2;
    size_t per = rc * 3072 * 4 + rc * (1024 + 152 + 256 + 128) * 2 + 8192;
    if (fixed + per <= ws_size || tcLog2 == 4) break;
  }
  const int Tc = 1 << tcLog2;
  const int NCk = TT / Tc;
  const size_t RC = (size_t)BB * Tc;

  char* ws = (char*)d_ws;
  size_t off = 0;
  auto alloc = [&](size_t bytes) -> char* {
    char* p = ws + off;
    off += (bytes + 255) & ~(size_t)255;
    return p;
  };

  unsigned* flags = (unsigned*)alloc(16 * 64 * sizeof(unsigned));
  u16* hbuf1 = (u16*)alloc((size_t)2 * 32 * 1024 * 2);
  u16* hbuf4 = (u16*)alloc((size_t)2 * 32 * 256 * 2);
  u16* hs2 = (u16*)alloc((size_t)32 * 128 * 2);
  u16* hs3 = (u16*)alloc((size_t)32 * 32 * 2);
  u16* hs5 = (u16*)alloc((size_t)32 * 128 * 2);
  u16* hs6 = (u16*)alloc((size_t)32 * 32 * 2);
  u16* recB[6];
  u16* gemB[6];
  for (int l = 0; l < 6; ++l) {
    recB[l] = (u16*)alloc(recB_elems[l] * 2);
    gemB[l] = (u16*)alloc(gemB_elems[l] * 2);
  }
  u16* x16 = (u16*)alloc((size_t)16384 * 512 * 2);
  float* xp = (float*)alloc(RC * 3072 * sizeof(float));
  u16* y1c = (u16*)alloc(RC * 1024 * 2);
  u16* ycc = (u16*)alloc(RC * 152 * 2);
  u16* y4c = (u16*)alloc(RC * 256 * 2);
  u16* y5c = (u16*)alloc(RC * 128 * 2);

  float* outye = (float*)d_out;
  float* outyd = outye + (size_t)BB * TT * 23;

  hipMemsetAsync(flags, 0, 16 * 64 * sizeof(unsigned), stream);
  hipMemsetAsync(ycc, 0, RC * 152 * 2, stream);  // keeps col 151 zero (K-pad for L4 GEMM)

  // prep: cast x, build all B-fragment arrays
  {
    int n4 = (16384 * 512) / 4;
    hipLaunchKernelGGL(cast_bf16, dim3((n4 + 255) / 256), dim3(256), 0, stream, x, x16, n4);
    for (int l = 0; l < 6; ++l) {
      const float* K = (const float*)d_in[1 + 3 * l];
      const float* R = (const float*)d_in[2 + 3 * l];
      int tfR = 3 * Ls[l].JT * Ls[l].KsR;
      hipLaunchKernelGGL(prep_frags, dim3((tfR * 64 + 255) / 256), dim3(256), 0, stream,
                         R, recB[l], 3 * Ls[l].U, Ls[l].U, Ls[l].KsR, Ls[l].JT, Ls[l].U, 1, tfR);
      int tfG = Ls[l].NtG * Ls[l].KsG;
      hipLaunchKernelGGL(prep_frags, dim3((tfG * 64 + 255) / 256), dim3(256), 0, stream,
                         K, gemB[l], Ls[l].N, Ls[l].Fi, Ls[l].KsG, 0, 0, 0, tfG);
    }
  }

  const u16* Ag[6] = {x16, y1c, ycc, ycc, y4c, y5c};
  const int sAg[6] = {512, 1024, 152, 152, 256, 128};
  u16* Ob[6] = {y1c, ycc, ycc + 128, y4c, y5c, nullptr};
  const int sOb[6] = {1024, 152, 152, 256, 128, 0};
  float* Of[6] = {nullptr, nullptr, outye, nullptr, nullptr, outyd};
  const int sOf[6] = {0, 0, 23, 0, 0, 8};

  int mslot = 0;
  for (int c = 0; c < NCk; ++c) {
    const int t0 = c * Tc;
    for (int l = 0; l < 6; ++l) {
      const LSpec& L = Ls[l];
      const float* bias = (const float*)d_in[3 + 3 * l];
      // input-projection GEMM for this chunk
      dim3 gg((L.NtG + 15) / 16, (unsigned)(RC / 16));
      hipLaunchKernelGGL(gemm_mfma, gg, dim3(256), 0, stream,
                         Ag[l], sAg[l], L.KactG, gemB[l], bias, xp,
                         L.N, L.NtG, L.KsG, (l == 0) ? t0 : -1, tcLog2);
      // recurrence
      const float* brec = bias + L.N;
      if (l == 0 || l == 3) {
        int nblk = (l == 0) ? 64 : 8;
        int nthr = (l == 0) ? 64 : 128;
        int swz = (l == 0) ? 1 : 0;
        int ush = (l == 0) ? 8 : 6;
        u16* hb = (l == 0) ? hbuf1 : hbuf4;
        unsigned* fl = flags + (size_t)mslot * 64;
        ++mslot;
        if (mslot >= 16) mslot = 0;  // slots reused across chunks is unsafe; but 16 = 2*8 chunks exactly
        hipLaunchKernelGGL(rec_multi, dim3(nblk), dim3(nthr), 0, stream,
                           xp, recB[l], brec, hb, Ob[l], sOb[l],
                           L.U, L.Kpad, L.KsR, L.JT, L.act, swz, ush,
                           fl, nblk, t0, Tc, (c == 0) ? 1 : 0);
      } else {
        u16* hs = (l == 1) ? hs2 : (l == 2) ? hs3 : (l == 4) ? hs5 : hs6;
        int nthr = (l == 1 || l == 4) ? 512 : (l == 2) ? 128 : 64;
        hipLaunchKernelGGL(rec_single, dim3(1), dim3(nthr), 0, stream,
                           xp, recB[l], brec, hs, Ob[l], sOb[l], Of[l], sOf[l],
                           L.U, L.Kpad, L.KsR, L.JT, L.act, t0, Tc, (c == 0) ? 1 : 0);
      }
    }
  }
}

// Round 5
// 27163.898 us; speedup vs baseline: 2.2488x; 1.4651x over previous
//
#include <hip/hip_runtime.h>
#include <hip/hip_bf16.h>
#include <cstdint>
#include <cstddef>

#define BB 32
#define TT 512

typedef short s8v __attribute__((ext_vector_type(8)));
typedef short s4v __attribute__((ext_vector_type(4)));
typedef float f4v __attribute__((ext_vector_type(4)));
typedef unsigned long long u64;
typedef unsigned short u16;
typedef unsigned int u32;

__device__ __forceinline__ short f2b(float x) {
  __hip_bfloat16 h = __float2bfloat16(x);
  return *reinterpret_cast<short*>(&h);
}
__device__ __forceinline__ float b2f(u16 x) {
  __hip_bfloat16 h = *reinterpret_cast<__hip_bfloat16*>(&x);
  return __bfloat162float(h);
}
__device__ __forceinline__ float sigm(float x) { return 1.f / (1.f + __expf(-x)); }

// LLC-coherent 16B load that the scheduler can pipeline (unlike atomic loads,
// which are ordered memory refs and serialize at ~400ns each — the R4 bug).
// Caller MUST vm_wait0() before using the result.
__device__ __forceinline__ f4v load16_sc(const void* p) {
  f4v v;
  asm volatile("global_load_dwordx4 %0, %1, off sc0 sc1" : "=v"(v) : "v"(p));
  return v;
}
__device__ __forceinline__ void vm_wait0() {
  asm volatile("s_waitcnt vmcnt(0)" ::: "memory");
}

// ---------------- grid barrier (flag array, LLC-coherent) ----------
__device__ __forceinline__ void gbar(unsigned* flags, int nblk, unsigned phase) {
  __syncthreads();  // compiler drains each wave's vmcnt before s_barrier
  if (threadIdx.x == 0)
    __hip_atomic_store(&flags[blockIdx.x], phase, __ATOMIC_RELEASE, __HIP_MEMORY_SCOPE_AGENT);
  for (;;) {
    int ok = 1;
    if ((int)threadIdx.x < nblk)
      ok = (__hip_atomic_load(&flags[threadIdx.x], __ATOMIC_RELAXED, __HIP_MEMORY_SCOPE_AGENT) >= phase) ? 1 : 0;
    if (__syncthreads_count(ok) == (int)blockDim.x) break;
    __builtin_amdgcn_s_sleep(1);
  }
}

// ---------------- x -> bf16 cast ----------------
__global__ __launch_bounds__(256) void cast_bf16(const float* __restrict__ in,
                                                 u16* __restrict__ outp, int n4) {
  int i = blockIdx.x * 256 + threadIdx.x;
  if (i < n4) {
    float4 v = *(const float4*)(in + (size_t)i * 4);
    u16 o[4] = {(u16)f2b(v.x), (u16)f2b(v.y), (u16)f2b(v.z), (u16)f2b(v.w)};
    *(u64*)(outp + (size_t)i * 4) = *(const u64*)o;
  }
}

// ---------------- weight -> MFMA B-fragment order (bf16) ----------------
__global__ __launch_bounds__(256) void prep_frags(const float* __restrict__ src,
                                                  u16* __restrict__ dst,
                                                  int N, int Ksrc, int Ks,
                                                  int JT, int U, int recmode, int total_fid) {
  int t = blockIdx.x * 256 + threadIdx.x;
  int lane = t & 63, fid = t >> 6;
  if (fid >= total_fid) return;
  int l15 = lane & 15, quad = lane >> 4;
  int ks = fid % Ks;
  int n, valid_n;
  if (recmode) {
    int rest = fid / Ks;
    int jt = rest % JT;
    int g = rest / JT;
    int jj = jt * 16 + l15;
    n = g * U + jj;
    valid_n = (jj < U) ? 1 : 0;
  } else {
    int nt = fid / Ks;
    n = nt * 16 + l15;
    valid_n = (n < N) ? 1 : 0;
  }
  u16* o = dst + ((size_t)fid * 64 + lane) * 8;
#pragma unroll
  for (int j = 0; j < 8; ++j) {
    int k = ks * 32 + quad * 8 + j;
    float v = (valid_n && k < Ksrc) ? src[(size_t)k * N + n] : 0.f;
    o[j] = (u16)f2b(v);
  }
}

// ---------------- MFMA GEMM: C[M,N] = A[M,Kact]_bf16 @ W + bias ----------------
__global__ __launch_bounds__(256) void gemm_mfma(const u16* __restrict__ A, int strideA, int Kact,
                                                 const u16* __restrict__ Bf,
                                                 const float* __restrict__ bias,
                                                 float* __restrict__ C,
                                                 int N, int Ntiles, int Ks,
                                                 int t0, int tcLog2) {
  __shared__ char sha[16 * 2056];
  const int tid = threadIdx.x;
  const int lane = tid & 63, l15 = lane & 15, quad = lane >> 4, w = tid >> 6;
  const int KS4 = Ks * 8;
  const int rowB = Ks * 64 + 8;
  const int bm = blockIdx.y * 16;

  for (int i = tid; i < 16 * KS4; i += 256) {
    int r = i / KS4, u = i - r * KS4;
    u64 v = 0;
    if (u * 4 < Kact) {
      int rl = bm + r;
      size_t grow;
      if (t0 >= 0) {
        int tcm = (1 << tcLog2) - 1;
        grow = (((size_t)(rl >> tcLog2)) << 9) + t0 + (rl & tcm);
      } else {
        grow = (size_t)rl;
      }
      v = *((const u64*)(A + grow * (size_t)strideA) + u);
    }
    *(u64*)(sha + r * rowB + u * 8) = v;
  }
  __syncthreads();

  f4v acc[4];
  f4v z4 = {0.f, 0.f, 0.f, 0.f};
#pragma unroll
  for (int q = 0; q < 4; ++q) acc[q] = z4;

  const int ntb = blockIdx.x * 16 + w * 4;
  for (int ks = 0; ks < Ks; ++ks) {
    int off = l15 * rowB + ks * 64 + quad * 16;
    s4v lo = *(const s4v*)(sha + off);
    s4v hi = *(const s4v*)(sha + off + 8);
    s8v a = __builtin_shufflevector(lo, hi, 0, 1, 2, 3, 4, 5, 6, 7);
#pragma unroll
    for (int q = 0; q < 4; ++q) {
      int nt = ntb + q;
      if (nt < Ntiles) {
        s8v b = *(const s8v*)(Bf + (((size_t)nt * Ks + ks) * 64 + lane) * 8);
        acc[q] = __builtin_amdgcn_mfma_f32_16x16x32_bf16(a, b, acc[q], 0, 0, 0);
      }
    }
  }
#pragma unroll
  for (int q = 0; q < 4; ++q) {
    int nt = ntb + q;
    if (nt >= Ntiles) continue;
    int col = nt * 16 + l15;
    if (col < N) {
      float bv = bias[col];
#pragma unroll
      for (int r = 0; r < 4; ++r) {
        int rowl = bm + quad * 4 + r;
        C[(size_t)rowl * N + col] = acc[q][r] + bv;
      }
    }
  }
}

// ---------------- L1 recurrence: U=1024, 8 blocks x 512 thr (wave owns 1 jt) -------
// hbuf: [2][32][1024] bf16 global, exchanged via sc1; h staged to LDS each step with
// pipelined sc-bypass loads. Weights stay L2-resident (plain loads).
__global__ __launch_bounds__(512) void rec_l1(const float* __restrict__ xp,
                                              const u16* __restrict__ Bf,
                                              const float* __restrict__ brec,
                                              u16* __restrict__ hbuf,
                                              u16* __restrict__ outb,
                                              unsigned* flags, int t0, int tc, int initH) {
  __shared__ char shm[32 * 2064];
  const int tid = threadIdx.x;
  const int lane = tid & 63, l15 = lane & 15, quad = tid >> 4 & 3;
  const int w = tid >> 6;
  const int jt = blockIdx.x * 8 + w;
  const int j = jt * 16 + l15;
  const int HP = 32 * 1024;

  unsigned phase = 1;
  if (initH) {
    u32* hz = (u32*)hbuf;
    for (int i = tid + blockIdx.x * 512; i < 32 * 1024; i += 8 * 512)
      __hip_atomic_store(hz + i, 0u, __ATOMIC_RELAXED, __HIP_MEMORY_SCOPE_AGENT);
  }
  gbar(flags, 8, phase++);

  const float bz = brec[j], brr = brec[1024 + j], bh = brec[2048 + j];
  float hprev[8];
  {
    const u32* hp = (const u32*)(hbuf + (size_t)(t0 & 1) * HP);
#pragma unroll
    for (int Mt = 0; Mt < 2; ++Mt)
#pragma unroll
      for (int r = 0; r < 4; ++r) {
        int b = Mt * 16 + quad * 4 + r;
        u32 wd = __hip_atomic_load(hp + ((b * 1024 + (j & ~1)) >> 1),
                                   __ATOMIC_RELAXED, __HIP_MEMORY_SCOPE_AGENT);
        hprev[Mt * 4 + r] = b2f((j & 1) ? (u16)(wd >> 16) : (u16)(wd & 0xffff));
      }
  }

  for (int tt = 0; tt < tc; ++tt) {
    const int t = t0 + tt;
    // xp prefetch (plain cached loads, independent of h)
    float xv[3][8];
#pragma unroll
    for (int Mt = 0; Mt < 2; ++Mt)
#pragma unroll
      for (int r = 0; r < 4; ++r) {
        int b = Mt * 16 + quad * 4 + r;
        const float* xr_ = xp + ((size_t)b * tc + tt) * 3072;
        xv[0][Mt * 4 + r] = xr_[j];
        xv[1][Mt * 4 + r] = xr_[1024 + j];
        xv[2][Mt * 4 + r] = xr_[2048 + j];
      }
    // stage h -> LDS: 64KB, 4096x16B units over 512 lanes = 8 pipelined loads/lane
    {
      const char* hsrc = (const char*)(hbuf + (size_t)(t & 1) * HP);
      f4v vals[8];
#pragma unroll
      for (int i = 0; i < 8; ++i)
        vals[i] = load16_sc(hsrc + (size_t)(tid + i * 512) * 16);
      vm_wait0();
#pragma unroll
      for (int i = 0; i < 8; ++i) {
        int g16 = tid + i * 512;
        int b = g16 >> 7;            // 128 x 16B per 2048B row
        int u = (g16 & 127) * 16;
        *(f4v*)(shm + b * 2064 + u) = vals[i];
      }
    }
    __syncthreads();
    // MFMA: ks outer, reuse b-frags across both M-tiles
    f4v acc[3][2];
    f4v z4 = {0.f, 0.f, 0.f, 0.f};
#pragma unroll
    for (int g = 0; g < 3; ++g) { acc[g][0] = z4; acc[g][1] = z4; }
    for (int ks = 0; ks < 32; ++ks) {
      s8v a0 = *(const s8v*)(shm + l15 * 2064 + ks * 64 + quad * 16);
      s8v a1 = *(const s8v*)(shm + (16 + l15) * 2064 + ks * 64 + quad * 16);
#pragma unroll
      for (int g = 0; g < 3; ++g) {
        s8v b = *(const s8v*)(Bf + (((size_t)(g * 64 + jt) * 32 + ks) * 64 + lane) * 8);
        acc[g][0] = __builtin_amdgcn_mfma_f32_16x16x32_bf16(a0, b, acc[g][0], 0, 0, 0);
        acc[g][1] = __builtin_amdgcn_mfma_f32_16x16x32_bf16(a1, b, acc[g][1], 0, 0, 0);
      }
    }
    // gates + publish
    u16* hdst = hbuf + (size_t)((t + 1) & 1) * HP;
#pragma unroll
    for (int Mt = 0; Mt < 2; ++Mt)
#pragma unroll
      for (int r = 0; r < 4; ++r) {
        int b = Mt * 16 + quad * 4 + r;
        size_t row = (size_t)b * tc + tt;
        float z = sigm(xv[0][Mt * 4 + r] + acc[0][Mt][r] + bz);
        float rr = sigm(xv[1][Mt * 4 + r] + acc[1][Mt][r] + brr);
        float hh = fmaxf(xv[2][Mt * 4 + r] + rr * (acc[2][Mt][r] + bh), 0.f);
        float hnew = z * hprev[Mt * 4 + r] + (1.f - z) * hh;
        hprev[Mt * 4 + r] = hnew;
        float part = __shfl_xor(hnew, 1, 64);
        if ((l15 & 1) == 0) {
          u32 wd = (u32)(u16)f2b(hnew) | ((u32)(u16)f2b(part) << 16);
          __hip_atomic_store((u32*)hdst + ((b * 1024 + j) >> 1), wd,
                             __ATOMIC_RELAXED, __HIP_MEMORY_SCOPE_AGENT);
          *((u32*)outb + ((row * 1024 + j) >> 1)) = wd;
        }
      }
    gbar(flags, 8, phase++);
    __syncthreads();  // LDS reuse: next stage writes after all waves' reads done
  }
}

// ---------------- single-block MFMA GRU recurrence (L2..L6) ----------------
// h double-buffered in LDS; persists across chunks via hsave. Wave handles up to
// JPW jt-tiles (jt = w + jj*NW).
__global__ __launch_bounds__(512) void rec_single(const float* __restrict__ xp,
                                                  const u16* __restrict__ Bf,
                                                  const float* __restrict__ brec,
                                                  u16* __restrict__ hsave,
                                                  u16* __restrict__ outb, int strideO,
                                                  float* __restrict__ outf, int strideF,
                                                  int U, int Kpad, int Ks, int JT, int JPW,
                                                  int act, int t0, int tc, int initH) {
  __shared__ char shs[33280];
  const int tid = threadIdx.x;
  const int lane = tid & 63, l15 = lane & 15, quad = lane >> 4;
  const int w = tid >> 6;
  const int NW = blockDim.x >> 6;
  const int S3U = 3 * U;
  const int rowB = Kpad * 2 + 8;
  const int HB = 32 * rowB;
  const int p0 = t0 & 1;

  for (int i = tid; i < (2 * HB) >> 2; i += blockDim.x) ((u32*)shs)[i] = 0;
  __syncthreads();
  if (!initH) {
    const int upr = Kpad >> 2;
    for (int i = tid; i < Kpad * 8; i += blockDim.x) {
      int m = i / upr, u = i - m * upr;
      *(u64*)(shs + p0 * HB + m * rowB + u * 8) = *((const u64*)hsave + i);
    }
  }
  __syncthreads();

  int jl[2];
  bool jv[2];
  float bz[2], brr[2], bh[2];
  float hprev[2][8];
#pragma unroll
  for (int jj = 0; jj < 2; ++jj) {
    int jt = w + jj * NW;
    bool val = (jj < JPW) && (jt < JT);
    int j = jt * 16 + l15;
    jv[jj] = val && (j < U);
    jl[jj] = jv[jj] ? j : 0;
    bz[jj] = jv[jj] ? brec[j] : 0.f;
    brr[jj] = jv[jj] ? brec[U + j] : 0.f;
    bh[jj] = jv[jj] ? brec[2 * U + j] : 0.f;
#pragma unroll
    for (int Mt = 0; Mt < 2; ++Mt)
#pragma unroll
      for (int r = 0; r < 4; ++r) {
        int b = Mt * 16 + quad * 4 + r;
        hprev[jj][Mt * 4 + r] =
            jv[jj] ? b2f(*(const u16*)(shs + p0 * HB + b * rowB + jl[jj] * 2)) : 0.f;
      }
  }

  for (int tt = 0; tt < tc; ++tt) {
    const int p = (t0 + tt) & 1;
    float xv[2][3][8];
#pragma unroll
    for (int jj = 0; jj < 2; ++jj)
#pragma unroll
      for (int Mt = 0; Mt < 2; ++Mt)
#pragma unroll
        for (int r = 0; r < 4; ++r) {
          int b = Mt * 16 + quad * 4 + r;
          const float* xr_ = xp + ((size_t)b * tc + tt) * S3U;
          xv[jj][0][Mt * 4 + r] = jv[jj] ? xr_[jl[jj]] : 0.f;
          xv[jj][1][Mt * 4 + r] = jv[jj] ? xr_[U + jl[jj]] : 0.f;
          xv[jj][2][Mt * 4 + r] = jv[jj] ? xr_[2 * U + jl[jj]] : 0.f;
        }
    f4v acc[2][3][2];
    f4v z4 = {0.f, 0.f, 0.f, 0.f};
#pragma unroll
    for (int jj = 0; jj < 2; ++jj)
#pragma unroll
      for (int g = 0; g < 3; ++g) { acc[jj][g][0] = z4; acc[jj][g][1] = z4; }
    for (int ks = 0; ks < Ks; ++ks) {
      s8v a[2];
#pragma unroll
      for (int Mt = 0; Mt < 2; ++Mt) {
        int off = p * HB + (Mt * 16 + l15) * rowB + (ks << 6) + (quad << 4);
        s4v lo = *(const s4v*)(shs + off);
        s4v hi = *(const s4v*)(shs + off + 8);
        a[Mt] = __builtin_shufflevector(lo, hi, 0, 1, 2, 3, 4, 5, 6, 7);
      }
#pragma unroll
      for (int jj = 0; jj < 2; ++jj) {
        if (jj >= JPW) break;
        int jt = w + jj * NW;
        if (jt >= JT) break;
#pragma unroll
        for (int g = 0; g < 3; ++g) {
          s8v b = *(const s8v*)(Bf + (((size_t)(g * JT + jt) * Ks + ks) * 64 + lane) * 8);
          acc[jj][g][0] = __builtin_amdgcn_mfma_f32_16x16x32_bf16(a[0], b, acc[jj][g][0], 0, 0, 0);
          acc[jj][g][1] = __builtin_amdgcn_mfma_f32_16x16x32_bf16(a[1], b, acc[jj][g][1], 0, 0, 0);
        }
      }
    }
#pragma unroll
    for (int jj = 0; jj < 2; ++jj) {
#pragma unroll
      for (int Mt = 0; Mt < 2; ++Mt)
#pragma unroll
        for (int r = 0; r < 4; ++r) {
          int b = Mt * 16 + quad * 4 + r;
          size_t row = (size_t)b * tc + tt;
          float z = sigm(xv[jj][0][Mt * 4 + r] + acc[jj][0][Mt][r] + bz[jj]);
          float rr = sigm(xv[jj][1][Mt * 4 + r] + acc[jj][1][Mt][r] + brr[jj]);
          float hh = xv[jj][2][Mt * 4 + r] + rr * (acc[jj][2][Mt][r] + bh[jj]);
          if (act) hh = fmaxf(hh, 0.f);
          float hnew = z * hprev[jj][Mt * 4 + r] + (1.f - z) * hh;
          hprev[jj][Mt * 4 + r] = hnew;
          int j = jl[jj];
          if (jv[jj]) *(u16*)(shs + (p ^ 1) * HB + b * rowB + j * 2) = (u16)f2b(hnew);
          float part = __shfl_xor(hnew, 1, 64);
          if (outb && jv[jj] && (l15 & 1) == 0) {
            float hi_v = ((j + 1) < U) ? part : 0.f;
            u32 wd = (u32)(u16)f2b(hnew) | ((u32)(u16)f2b(hi_v) << 16);
            *((u32*)outb + ((row * strideO + j) >> 1)) = wd;
          }
          if (outf && jv[jj]) outf[((size_t)b * TT + t0 + tt) * strideF + j] = hnew;
        }
    }
    __syncthreads();
  }
  {
    const int pf = (t0 + tc) & 1;
    const int upr = Kpad >> 2;
    for (int i = tid; i < Kpad * 8; i += blockDim.x) {
      int m = i / upr, u = i - m * upr;
      *((u64*)hsave + i) = *(const u64*)(shs + pf * HB + m * rowB + u * 8);
    }
  }
}

// ---------------- host launch ----------------
extern "C" void kernel_launch(void* const* d_in, const int* in_sizes, int n_in,
                              void* d_out, int out_size, void* d_ws, size_t ws_size,
                              hipStream_t stream) {
  const float* x = (const float*)d_in[0];
  struct LSpec {
    int Fi, U, act;
    int Kpad, KsR, JT;      // recurrence
    int N, NtG, KsG, KactG; // input-proj gemm
  };
  const LSpec Ls[6] = {
      {512, 1024, 1, 1024, 32, 64, 3072, 192, 16, 512},
      {1024, 128, 1, 128, 4, 8, 384, 24, 32, 1024},
      {128, 23, 0, 32, 1, 2, 69, 5, 4, 128},
      {151, 256, 1, 256, 8, 16, 768, 48, 5, 152},
      {256, 128, 1, 128, 4, 8, 384, 24, 8, 256},
      {128, 8, 0, 32, 1, 1, 24, 2, 4, 128}};
  // rec_single config: threads, JPW
  const int snthr[6] = {0, 512, 128, 512, 512, 64};
  const int sjpw[6] = {0, 1, 1, 2, 1, 1};

  size_t recB_elems[6], gemB_elems[6];
  size_t fixed = 0;
  for (int l = 0; l < 6; ++l) {
    recB_elems[l] = (size_t)3 * Ls[l].JT * Ls[l].KsR * 512;
    gemB_elems[l] = (size_t)Ls[l].NtG * Ls[l].KsG * 512;
    fixed += (recB_elems[l] + gemB_elems[l]) * 2 + 512;
  }
  fixed += 8 * 64 * 4 + 4096;
  fixed += (size_t)2 * 32 * 1024 * 2 + 1024;
  fixed += (size_t)32 * (128 + 32 + 256 + 128 + 32) * 2 + 2048;
  fixed += (size_t)16384 * 512 * 2 + 256;
  int tcLog2 = 6;
  for (; tcLog2 >= 4; --tcLog2) {
    size_t rc = (size_t)BB << tcLog2;
    size_t per = rc * 3072 * 4 + rc * (1024 + 152 + 256 + 128) * 2 + 8192;
    if (fixed + per <= ws_size || tcLog2 == 4) break;
  }
  const int Tc = 1 << tcLog2;
  const int NCk = TT / Tc;
  const size_t RC = (size_t)BB * Tc;

  char* ws = (char*)d_ws;
  size_t off = 0;
  auto alloc = [&](size_t bytes) -> char* {
    char* p = ws + off;
    off += (bytes + 255) & ~(size_t)255;
    return p;
  };

  unsigned* flags = (unsigned*)alloc(8 * 64 * sizeof(unsigned));
  u16* hbuf1 = (u16*)alloc((size_t)2 * 32 * 1024 * 2);
  u16* hsv[6];
  hsv[0] = nullptr;
  hsv[1] = (u16*)alloc((size_t)32 * 128 * 2);
  hsv[2] = (u16*)alloc((size_t)32 * 32 * 2);
  hsv[3] = (u16*)alloc((size_t)32 * 256 * 2);
  hsv[4] = (u16*)alloc((size_t)32 * 128 * 2);
  hsv[5] = (u16*)alloc((size_t)32 * 32 * 2);
  u16* recB[6];
  u16* gemB[6];
  for (int l = 0; l < 6; ++l) {
    recB[l] = (u16*)alloc(recB_elems[l] * 2);
    gemB[l] = (u16*)alloc(gemB_elems[l] * 2);
  }
  u16* x16 = (u16*)alloc((size_t)16384 * 512 * 2);
  float* xp = (float*)alloc(RC * 3072 * sizeof(float));
  u16* y1c = (u16*)alloc(RC * 1024 * 2);
  u16* ycc = (u16*)alloc(RC * 152 * 2);
  u16* y4c = (u16*)alloc(RC * 256 * 2);
  u16* y5c = (u16*)alloc(RC * 128 * 2);

  float* outye = (float*)d_out;
  float* outyd = outye + (size_t)BB * TT * 23;

  hipMemsetAsync(flags, 0, 8 * 64 * sizeof(unsigned), stream);
  hipMemsetAsync(ycc, 0, RC * 152 * 2, stream);  // col 151 stays zero (K-pad for L4 GEMM)

  {
    int n4 = (16384 * 512) / 4;
    hipLaunchKernelGGL(cast_bf16, dim3((n4 + 255) / 256), dim3(256), 0, stream, x, x16, n4);
    for (int l = 0; l < 6; ++l) {
      const float* K = (const float*)d_in[1 + 3 * l];
      const float* R = (const float*)d_in[2 + 3 * l];
      int tfR = 3 * Ls[l].JT * Ls[l].KsR;
      hipLaunchKernelGGL(prep_frags, dim3((tfR * 64 + 255) / 256), dim3(256), 0, stream,
                         R, recB[l], 3 * Ls[l].U, Ls[l].U, Ls[l].KsR, Ls[l].JT, Ls[l].U, 1, tfR);
      int tfG = Ls[l].NtG * Ls[l].KsG;
      hipLaunchKernelGGL(prep_frags, dim3((tfG * 64 + 255) / 256), dim3(256), 0, stream,
                         K, gemB[l], Ls[l].N, Ls[l].Fi, Ls[l].KsG, 0, 0, 0, tfG);
    }
  }

  const u16* Ag[6] = {x16, y1c, ycc, ycc, y4c, y5c};
  const int sAg[6] = {512, 1024, 152, 152, 256, 128};
  u16* Ob[6] = {y1c, ycc, ycc + 128, y4c, y5c, nullptr};
  const int sOb[6] = {1024, 152, 152, 256, 128, 0};
  float* Of[6] = {nullptr, nullptr, outye, nullptr, nullptr, outyd};
  const int sOf[6] = {0, 0, 23, 0, 0, 8};

  for (int c = 0; c < NCk; ++c) {
    const int t0 = c * Tc;
    for (int l = 0; l < 6; ++l) {
      const LSpec& L = Ls[l];
      const float* bias = (const float*)d_in[3 + 3 * l];
      dim3 gg((L.NtG + 15) / 16, (unsigned)(RC / 16));
      hipLaunchKernelGGL(gemm_mfma, gg, dim3(256), 0, stream,
                         Ag[l], sAg[l], L.KactG, gemB[l], bias, xp,
                         L.N, L.NtG, L.KsG, (l == 0) ? t0 : -1, tcLog2);
      const float* brec = bias + L.N;
      if (l == 0) {
        hipLaunchKernelGGL(rec_l1, dim3(8), dim3(512), 0, stream,
                           xp, recB[0], brec, hbuf1, y1c,
                           flags + (size_t)c * 64, t0, Tc, (c == 0) ? 1 : 0);
      } else {
        hipLaunchKernelGGL(rec_single, dim3(1), dim3(snthr[l]), 0, stream,
                           xp, recB[l], brec, hsv[l], Ob[l], sOb[l], Of[l], sOf[l],
                           L.U, L.Kpad, L.KsR, L.JT, sjpw[l], L.act, t0, Tc,
                           (c == 0) ? 1 : 0);
      }
    }
  }
}

// Round 6
// 22500.258 us; speedup vs baseline: 2.7149x; 1.2073x over previous
//
#include <hip/hip_runtime.h>
#include <hip/hip_bf16.h>
#include <cstdint>
#include <cstddef>

#define BB 32
#define TT 512

typedef short s8v __attribute__((ext_vector_type(8)));
typedef short s4v __attribute__((ext_vector_type(4)));
typedef float f4v __attribute__((ext_vector_type(4)));
typedef unsigned long long u64;
typedef unsigned short u16;
typedef unsigned int u32;

__device__ __forceinline__ short f2b(float x) {
  __hip_bfloat16 h = __float2bfloat16(x);
  return *reinterpret_cast<short*>(&h);
}
__device__ __forceinline__ float b2f(u16 x) {
  __hip_bfloat16 h = *reinterpret_cast<__hip_bfloat16*>(&x);
  return __bfloat162float(h);
}
__device__ __forceinline__ float sigm(float x) { return 1.f / (1.f + __expf(-x)); }

// LLC-coherent 16B load the scheduler can pipeline (atomic loads serialize).
// Caller MUST vm_wait0() before using the result.
__device__ __forceinline__ f4v load16_sc(const void* p) {
  f4v v;
  asm volatile("global_load_dwordx4 %0, %1, off sc0 sc1" : "=v"(v) : "v"(p));
  return v;
}
__device__ __forceinline__ void vm_wait0() {
  asm volatile("s_waitcnt vmcnt(0)" ::: "memory");
}

// ---------------- grid barrier (flag array, LLC-coherent) ----------
__device__ __forceinline__ void gbar(unsigned* flags, int nblk, unsigned phase) {
  __syncthreads();
  if (threadIdx.x == 0)
    __hip_atomic_store(&flags[blockIdx.x], phase, __ATOMIC_RELEASE, __HIP_MEMORY_SCOPE_AGENT);
  for (;;) {
    int ok = 1;
    if ((int)threadIdx.x < nblk)
      ok = (__hip_atomic_load(&flags[threadIdx.x], __ATOMIC_RELAXED, __HIP_MEMORY_SCOPE_AGENT) >= phase) ? 1 : 0;
    if (__syncthreads_count(ok) == (int)blockDim.x) break;
    __builtin_amdgcn_s_sleep(1);
  }
}

// ---------------- x -> bf16 cast ----------------
__global__ __launch_bounds__(256) void cast_bf16(const float* __restrict__ in,
                                                 u16* __restrict__ outp, int n4) {
  int i = blockIdx.x * 256 + threadIdx.x;
  if (i < n4) {
    float4 v = *(const float4*)(in + (size_t)i * 4);
    u16 o[4] = {(u16)f2b(v.x), (u16)f2b(v.y), (u16)f2b(v.z), (u16)f2b(v.w)};
    *(u64*)(outp + (size_t)i * 4) = *(const u64*)o;
  }
}

// ---------------- weight -> MFMA B-fragment order (bf16) ----------------
__global__ __launch_bounds__(256) void prep_frags(const float* __restrict__ src,
                                                  u16* __restrict__ dst,
                                                  int N, int Ksrc, int Ks,
                                                  int JT, int U, int recmode, int total_fid) {
  int t = blockIdx.x * 256 + threadIdx.x;
  int lane = t & 63, fid = t >> 6;
  if (fid >= total_fid) return;
  int l15 = lane & 15, quad = lane >> 4;
  int ks = fid % Ks;
  int n, valid_n;
  if (recmode) {
    int rest = fid / Ks;
    int jt = rest % JT;
    int g = rest / JT;
    int jj = jt * 16 + l15;
    n = g * U + jj;
    valid_n = (jj < U) ? 1 : 0;
  } else {
    int nt = fid / Ks;
    n = nt * 16 + l15;
    valid_n = (n < N) ? 1 : 0;
  }
  u16* o = dst + ((size_t)fid * 64 + lane) * 8;
#pragma unroll
  for (int j = 0; j < 8; ++j) {
    int k = ks * 32 + quad * 8 + j;
    float v = (valid_n && k < Ksrc) ? src[(size_t)k * N + n] : 0.f;
    o[j] = (u16)f2b(v);
  }
}

// ---------------- MFMA GEMM: C[M,N] = A[M,Kact]_bf16 @ W + bias ----------------
__global__ __launch_bounds__(256) void gemm_mfma(const u16* __restrict__ A, int strideA, int Kact,
                                                 const u16* __restrict__ Bf,
                                                 const float* __restrict__ bias,
                                                 float* __restrict__ C,
                                                 int N, int Ntiles, int Ks,
                                                 int t0, int tcLog2) {
  __shared__ char sha[16 * 2056];
  const int tid = threadIdx.x;
  const int lane = tid & 63, l15 = lane & 15, quad = lane >> 4, w = tid >> 6;
  const int KS4 = Ks * 8;
  const int rowB = Ks * 64 + 8;
  const int bm = blockIdx.y * 16;

  for (int i = tid; i < 16 * KS4; i += 256) {
    int r = i / KS4, u = i - r * KS4;
    u64 v = 0;
    if (u * 4 < Kact) {
      int rl = bm + r;
      size_t grow;
      if (t0 >= 0) {
        int tcm = (1 << tcLog2) - 1;
        grow = (((size_t)(rl >> tcLog2)) << 9) + t0 + (rl & tcm);
      } else {
        grow = (size_t)rl;
      }
      v = *((const u64*)(A + grow * (size_t)strideA) + u);
    }
    *(u64*)(sha + r * rowB + u * 8) = v;
  }
  __syncthreads();

  f4v acc[4];
  f4v z4 = {0.f, 0.f, 0.f, 0.f};
#pragma unroll
  for (int q = 0; q < 4; ++q) acc[q] = z4;

  const int ntb = blockIdx.x * 16 + w * 4;
  for (int ks = 0; ks < Ks; ++ks) {
    int off = l15 * rowB + ks * 64 + quad * 16;
    s4v lo = *(const s4v*)(sha + off);
    s4v hi = *(const s4v*)(sha + off + 8);
    s8v a = __builtin_shufflevector(lo, hi, 0, 1, 2, 3, 4, 5, 6, 7);
#pragma unroll
    for (int q = 0; q < 4; ++q) {
      int nt = ntb + q;
      if (nt < Ntiles) {
        s8v b = *(const s8v*)(Bf + (((size_t)nt * Ks + ks) * 64 + lane) * 8);
        acc[q] = __builtin_amdgcn_mfma_f32_16x16x32_bf16(a, b, acc[q], 0, 0, 0);
      }
    }
  }
#pragma unroll
  for (int q = 0; q < 4; ++q) {
    int nt = ntb + q;
    if (nt >= Ntiles) continue;
    int col = nt * 16 + l15;
    if (col < N) {
      float bv = bias[col];
#pragma unroll
      for (int r = 0; r < 4; ++r) {
        int rowl = bm + quad * 4 + r;
        C[(size_t)rowl * N + col] = acc[q][r] + bv;
      }
    }
  }
}

// ---------------- L1 recurrence: U=1024, 16 blocks x 256 thr (wave owns 1 jt) ------
// hbuf: [2][32][1024] bf16 global via sc1. xp read with NT loads (keeps the 393KB
// per-block weight slice L2-resident). ks loop unrolled x4 for load MLP.
__global__ __launch_bounds__(256) void rec_l1(const float* __restrict__ xp,
                                              const u16* __restrict__ Bf,
                                              const float* __restrict__ brec,
                                              u16* __restrict__ hbuf,
                                              u16* __restrict__ outb,
                                              unsigned* flags, int t0, int tc, int initH) {
  __shared__ char shm[32 * 2064];
  const int tid = threadIdx.x;
  const int lane = tid & 63, l15 = lane & 15, quad = (lane >> 4) & 3;
  const int w = tid >> 6;
  const int jt = blockIdx.x * 4 + w;
  const int j = jt * 16 + l15;
  const int HP = 32 * 1024;

  unsigned phase = 1;
  if (initH) {
    u32* hz = (u32*)hbuf;
    for (int i = tid + blockIdx.x * 256; i < 32 * 1024; i += 16 * 256)
      __hip_atomic_store(hz + i, 0u, __ATOMIC_RELAXED, __HIP_MEMORY_SCOPE_AGENT);
  }
  gbar(flags, 16, phase++);

  const float bz = brec[j], brr = brec[1024 + j], bh = brec[2048 + j];
  float hprev[8];
  {
    const u32* hp = (const u32*)(hbuf + (size_t)(t0 & 1) * HP);
#pragma unroll
    for (int Mt = 0; Mt < 2; ++Mt)
#pragma unroll
      for (int r = 0; r < 4; ++r) {
        int b = Mt * 16 + quad * 4 + r;
        u32 wd = __hip_atomic_load(hp + ((b * 1024 + (j & ~1)) >> 1),
                                   __ATOMIC_RELAXED, __HIP_MEMORY_SCOPE_AGENT);
        hprev[Mt * 4 + r] = b2f((j & 1) ? (u16)(wd >> 16) : (u16)(wd & 0xffff));
      }
  }

  for (int tt = 0; tt < tc; ++tt) {
    const int t = t0 + tt;
    // xp prefetch: NT loads — do not pollute L2 (weights must stay resident)
    float xv[3][8];
#pragma unroll
    for (int Mt = 0; Mt < 2; ++Mt)
#pragma unroll
      for (int r = 0; r < 4; ++r) {
        int b = Mt * 16 + quad * 4 + r;
        const float* xr_ = xp + ((size_t)b * tc + tt) * 3072;
        xv[0][Mt * 4 + r] = __builtin_nontemporal_load(xr_ + j);
        xv[1][Mt * 4 + r] = __builtin_nontemporal_load(xr_ + 1024 + j);
        xv[2][Mt * 4 + r] = __builtin_nontemporal_load(xr_ + 2048 + j);
      }
    // stage h -> LDS: 64KB = 4096 x 16B over 256 lanes, 2 pipelined batches of 8
    {
      const char* hsrc = (const char*)(hbuf + (size_t)(t & 1) * HP);
      f4v vals[8];
#pragma unroll
      for (int i = 0; i < 8; ++i)
        vals[i] = load16_sc(hsrc + (size_t)(tid + i * 256) * 16);
      vm_wait0();
#pragma unroll
      for (int i = 0; i < 8; ++i) {
        int g16 = tid + i * 256;
        *(f4v*)(shm + (g16 >> 7) * 2064 + (g16 & 127) * 16) = vals[i];
      }
#pragma unroll
      for (int i = 0; i < 8; ++i)
        vals[i] = load16_sc(hsrc + (size_t)(tid + (i + 8) * 256) * 16);
      vm_wait0();
#pragma unroll
      for (int i = 0; i < 8; ++i) {
        int g16 = tid + (i + 8) * 256;
        *(f4v*)(shm + (g16 >> 7) * 2064 + (g16 & 127) * 16) = vals[i];
      }
    }
    __syncthreads();
    // MFMA: ks outer, unroll 4 for b-frag load MLP
    f4v acc[3][2];
    f4v z4 = {0.f, 0.f, 0.f, 0.f};
#pragma unroll
    for (int g = 0; g < 3; ++g) { acc[g][0] = z4; acc[g][1] = z4; }
#pragma unroll 4
    for (int ks = 0; ks < 32; ++ks) {
      s8v a0 = *(const s8v*)(shm + l15 * 2064 + ks * 64 + quad * 16);
      s8v a1 = *(const s8v*)(shm + (16 + l15) * 2064 + ks * 64 + quad * 16);
#pragma unroll
      for (int g = 0; g < 3; ++g) {
        s8v b = *(const s8v*)(Bf + (((size_t)(g * 64 + jt) * 32 + ks) * 64 + lane) * 8);
        acc[g][0] = __builtin_amdgcn_mfma_f32_16x16x32_bf16(a0, b, acc[g][0], 0, 0, 0);
        acc[g][1] = __builtin_amdgcn_mfma_f32_16x16x32_bf16(a1, b, acc[g][1], 0, 0, 0);
      }
    }
    // gates + publish
    u16* hdst = hbuf + (size_t)((t + 1) & 1) * HP;
#pragma unroll
    for (int Mt = 0; Mt < 2; ++Mt)
#pragma unroll
      for (int r = 0; r < 4; ++r) {
        int b = Mt * 16 + quad * 4 + r;
        size_t row = (size_t)b * tc + tt;
        float z = sigm(xv[0][Mt * 4 + r] + acc[0][Mt][r] + bz);
        float rr = sigm(xv[1][Mt * 4 + r] + acc[1][Mt][r] + brr);
        float hh = fmaxf(xv[2][Mt * 4 + r] + rr * (acc[2][Mt][r] + bh), 0.f);
        float hnew = z * hprev[Mt * 4 + r] + (1.f - z) * hh;
        hprev[Mt * 4 + r] = hnew;
        float part = __shfl_xor(hnew, 1, 64);
        if ((l15 & 1) == 0) {
          u32 wd = (u32)(u16)f2b(hnew) | ((u32)(u16)f2b(part) << 16);
          __hip_atomic_store((u32*)hdst + ((b * 1024 + j) >> 1), wd,
                             __ATOMIC_RELAXED, __HIP_MEMORY_SCOPE_AGENT);
          *((u32*)outb + ((row * 1024 + j) >> 1)) = wd;
        }
      }
    gbar(flags, 16, phase++);
  }
}

// ---------------- single-block MFMA GRU recurrence (L2..L6) ----------------
__global__ __launch_bounds__(512) void rec_single(const float* __restrict__ xp,
                                                  const u16* __restrict__ Bf,
                                                  const float* __restrict__ brec,
                                                  u16* __restrict__ hsave,
                                                  u16* __restrict__ outb, int strideO,
                                                  float* __restrict__ outf, int strideF,
                                                  int U, int Kpad, int Ks, int JT, int JPW,
                                                  int act, int t0, int tc, int initH) {
  __shared__ char shs[33280];
  const int tid = threadIdx.x;
  const int lane = tid & 63, l15 = lane & 15, quad = lane >> 4;
  const int w = tid >> 6;
  const int NW = blockDim.x >> 6;
  const int S3U = 3 * U;
  const int rowB = Kpad * 2 + 8;
  const int HB = 32 * rowB;
  const int p0 = t0 & 1;

  for (int i = tid; i < (2 * HB) >> 2; i += blockDim.x) ((u32*)shs)[i] = 0;
  __syncthreads();
  if (!initH) {
    const int upr = Kpad >> 2;
    for (int i = tid; i < Kpad * 8; i += blockDim.x) {
      int m = i / upr, u = i - m * upr;
      *(u64*)(shs + p0 * HB + m * rowB + u * 8) = *((const u64*)hsave + i);
    }
  }
  __syncthreads();

  int jl[2];
  bool jv[2];
  float bz[2], brr[2], bh[2];
  float hprev[2][8];
#pragma unroll
  for (int jj = 0; jj < 2; ++jj) {
    int jt = w + jj * NW;
    bool val = (jj < JPW) && (jt < JT);
    int j = jt * 16 + l15;
    jv[jj] = val && (j < U);
    jl[jj] = jv[jj] ? j : 0;
    bz[jj] = jv[jj] ? brec[j] : 0.f;
    brr[jj] = jv[jj] ? brec[U + j] : 0.f;
    bh[jj] = jv[jj] ? brec[2 * U + j] : 0.f;
#pragma unroll
    for (int Mt = 0; Mt < 2; ++Mt)
#pragma unroll
      for (int r = 0; r < 4; ++r) {
        int b = Mt * 16 + quad * 4 + r;
        hprev[jj][Mt * 4 + r] =
            jv[jj] ? b2f(*(const u16*)(shs + p0 * HB + b * rowB + jl[jj] * 2)) : 0.f;
      }
  }

  for (int tt = 0; tt < tc; ++tt) {
    const int p = (t0 + tt) & 1;
    float xv[2][3][8];
#pragma unroll
    for (int jj = 0; jj < 2; ++jj)
#pragma unroll
      for (int Mt = 0; Mt < 2; ++Mt)
#pragma unroll
        for (int r = 0; r < 4; ++r) {
          int b = Mt * 16 + quad * 4 + r;
          const float* xr_ = xp + ((size_t)b * tc + tt) * S3U;
          xv[jj][0][Mt * 4 + r] = jv[jj] ? __builtin_nontemporal_load(xr_ + jl[jj]) : 0.f;
          xv[jj][1][Mt * 4 + r] = jv[jj] ? __builtin_nontemporal_load(xr_ + U + jl[jj]) : 0.f;
          xv[jj][2][Mt * 4 + r] = jv[jj] ? __builtin_nontemporal_load(xr_ + 2 * U + jl[jj]) : 0.f;
        }
    f4v acc[2][3][2];
    f4v z4 = {0.f, 0.f, 0.f, 0.f};
#pragma unroll
    for (int jj = 0; jj < 2; ++jj)
#pragma unroll
      for (int g = 0; g < 3; ++g) { acc[jj][g][0] = z4; acc[jj][g][1] = z4; }
#pragma unroll 2
    for (int ks = 0; ks < Ks; ++ks) {
      s8v a[2];
#pragma unroll
      for (int Mt = 0; Mt < 2; ++Mt) {
        int off = p * HB + (Mt * 16 + l15) * rowB + (ks << 6) + (quad << 4);
        s4v lo = *(const s4v*)(shs + off);
        s4v hi = *(const s4v*)(shs + off + 8);
        a[Mt] = __builtin_shufflevector(lo, hi, 0, 1, 2, 3, 4, 5, 6, 7);
      }
#pragma unroll
      for (int jj = 0; jj < 2; ++jj) {
        if (jj >= JPW) break;
        int jt = w + jj * NW;
        if (jt >= JT) break;
#pragma unroll
        for (int g = 0; g < 3; ++g) {
          s8v b = *(const s8v*)(Bf + (((size_t)(g * JT + jt) * Ks + ks) * 64 + lane) * 8);
          acc[jj][g][0] = __builtin_amdgcn_mfma_f32_16x16x32_bf16(a[0], b, acc[jj][g][0], 0, 0, 0);
          acc[jj][g][1] = __builtin_amdgcn_mfma_f32_16x16x32_bf16(a[1], b, acc[jj][g][1], 0, 0, 0);
        }
      }
    }
#pragma unroll
    for (int jj = 0; jj < 2; ++jj) {
#pragma unroll
      for (int Mt = 0; Mt < 2; ++Mt)
#pragma unroll
        for (int r = 0; r < 4; ++r) {
          int b = Mt * 16 + quad * 4 + r;
          size_t row = (size_t)b * tc + tt;
          float z = sigm(xv[jj][0][Mt * 4 + r] + acc[jj][0][Mt][r] + bz[jj]);
          float rr = sigm(xv[jj][1][Mt * 4 + r] + acc[jj][1][Mt][r] + brr[jj]);
          float hh = xv[jj][2][Mt * 4 + r] + rr * (acc[jj][2][Mt][r] + bh[jj]);
          if (act) hh = fmaxf(hh, 0.f);
          float hnew = z * hprev[jj][Mt * 4 + r] + (1.f - z) * hh;
          hprev[jj][Mt * 4 + r] = hnew;
          int j = jl[jj];
          if (jv[jj]) *(u16*)(shs + (p ^ 1) * HB + b * rowB + j * 2) = (u16)f2b(hnew);
          float part = __shfl_xor(hnew, 1, 64);
          if (outb && jv[jj] && (l15 & 1) == 0) {
            float hi_v = ((j + 1) < U) ? part : 0.f;
            u32 wd = (u32)(u16)f2b(hnew) | ((u32)(u16)f2b(hi_v) << 16);
            *((u32*)outb + ((row * strideO + j) >> 1)) = wd;
          }
          if (outf && jv[jj]) outf[((size_t)b * TT + t0 + tt) * strideF + j] = hnew;
        }
    }
    __syncthreads();
  }
  {
    const int pf = (t0 + tc) & 1;
    const int upr = Kpad >> 2;
    for (int i = tid; i < Kpad * 8; i += blockDim.x) {
      int m = i / upr, u = i - m * upr;
      *((u64*)hsave + i) = *(const u64*)(shs + pf * HB + m * rowB + u * 8);
    }
  }
}

// ---------------- host launch ----------------
extern "C" void kernel_launch(void* const* d_in, const int* in_sizes, int n_in,
                              void* d_out, int out_size, void* d_ws, size_t ws_size,
                              hipStream_t stream) {
  const float* x = (const float*)d_in[0];
  struct LSpec {
    int Fi, U, act;
    int Kpad, KsR, JT;      // recurrence
    int N, NtG, KsG, KactG; // input-proj gemm
  };
  const LSpec Ls[6] = {
      {512, 1024, 1, 1024, 32, 64, 3072, 192, 16, 512},
      {1024, 128, 1, 128, 4, 8, 384, 24, 32, 1024},
      {128, 23, 0, 32, 1, 2, 69, 5, 4, 128},
      {151, 256, 1, 256, 8, 16, 768, 48, 5, 152},
      {256, 128, 1, 128, 4, 8, 384, 24, 8, 256},
      {128, 8, 0, 32, 1, 1, 24, 2, 4, 128}};
  const int snthr[6] = {0, 512, 128, 512, 512, 64};
  const int sjpw[6] = {0, 1, 1, 2, 1, 1};

  size_t recB_elems[6], gemB_elems[6];
  size_t fixed = 0;
  for (int l = 0; l < 6; ++l) {
    recB_elems[l] = (size_t)3 * Ls[l].JT * Ls[l].KsR * 512;
    gemB_elems[l] = (size_t)Ls[l].NtG * Ls[l].KsG * 512;
    fixed += (recB_elems[l] + gemB_elems[l]) * 2 + 512;
  }
  fixed += 8 * 64 * 4 + 4096;
  fixed += (size_t)2 * 32 * 1024 * 2 + 1024;
  fixed += (size_t)32 * (128 + 32 + 256 + 128 + 32) * 2 + 2048;
  fixed += (size_t)16384 * 512 * 2 + 256;
  int tcLog2 = 6;
  for (; tcLog2 >= 4; --tcLog2) {
    size_t rc = (size_t)BB << tcLog2;
    size_t per = rc * 3072 * 4 + rc * (1024 + 152 + 256 + 128) * 2 + 8192;
    if (fixed + per <= ws_size || tcLog2 == 4) break;
  }
  const int Tc = 1 << tcLog2;
  const int NCk = TT / Tc;
  const size_t RC = (size_t)BB * Tc;

  char* ws = (char*)d_ws;
  size_t off = 0;
  auto alloc = [&](size_t bytes) -> char* {
    char* p = ws + off;
    off += (bytes + 255) & ~(size_t)255;
    return p;
  };

  unsigned* flags = (unsigned*)alloc(8 * 64 * sizeof(unsigned));
  u16* hbuf1 = (u16*)alloc((size_t)2 * 32 * 1024 * 2);
  u16* hsv[6];
  hsv[0] = nullptr;
  hsv[1] = (u16*)alloc((size_t)32 * 128 * 2);
  hsv[2] = (u16*)alloc((size_t)32 * 32 * 2);
  hsv[3] = (u16*)alloc((size_t)32 * 256 * 2);
  hsv[4] = (u16*)alloc((size_t)32 * 128 * 2);
  hsv[5] = (u16*)alloc((size_t)32 * 32 * 2);
  u16* recB[6];
  u16* gemB[6];
  for (int l = 0; l < 6; ++l) {
    recB[l] = (u16*)alloc(recB_elems[l] * 2);
    gemB[l] = (u16*)alloc(gemB_elems[l] * 2);
  }
  u16* x16 = (u16*)alloc((size_t)16384 * 512 * 2);
  float* xp = (float*)alloc(RC * 3072 * sizeof(float));
  u16* y1c = (u16*)alloc(RC * 1024 * 2);
  u16* ycc = (u16*)alloc(RC * 152 * 2);
  u16* y4c = (u16*)alloc(RC * 256 * 2);
  u16* y5c = (u16*)alloc(RC * 128 * 2);

  float* outye = (float*)d_out;
  float* outyd = outye + (size_t)BB * TT * 23;

  hipMemsetAsync(flags, 0, 8 * 64 * sizeof(unsigned), stream);
  hipMemsetAsync(ycc, 0, RC * 152 * 2, stream);  // col 151 stays zero (K-pad for L4 GEMM)

  {
    int n4 = (16384 * 512) / 4;
    hipLaunchKernelGGL(cast_bf16, dim3((n4 + 255) / 256), dim3(256), 0, stream, x, x16, n4);
    for (int l = 0; l < 6; ++l) {
      const float* K = (const float*)d_in[1 + 3 * l];
      const float* R = (const float*)d_in[2 + 3 * l];
      int tfR = 3 * Ls[l].JT * Ls[l].KsR;
      hipLaunchKernelGGL(prep_frags, dim3((tfR * 64 + 255) / 256), dim3(256), 0, stream,
                         R, recB[l], 3 * Ls[l].U, Ls[l].U, Ls[l].KsR, Ls[l].JT, Ls[l].U, 1, tfR);
      int tfG = Ls[l].NtG * Ls[l].KsG;
      hipLaunchKernelGGL(prep_frags, dim3((tfG * 64 + 255) / 256), dim3(256), 0, stream,
                         K, gemB[l], Ls[l].N, Ls[l].Fi, Ls[l].KsG, 0, 0, 0, tfG);
    }
  }

  const u16* Ag[6] = {x16, y1c, ycc, ycc, y4c, y5c};
  const int sAg[6] = {512, 1024, 152, 152, 256, 128};
  u16* Ob[6] = {y1c, ycc, ycc + 128, y4c, y5c, nullptr};
  const int sOb[6] = {1024, 152, 152, 256, 128, 0};
  float* Of[6] = {nullptr, nullptr, outye, nullptr, nullptr, outyd};
  const int sOf[6] = {0, 0, 23, 0, 0, 8};

  for (int c = 0; c < NCk; ++c) {
    const int t0 = c * Tc;
    for (int l = 0; l < 6; ++l) {
      const LSpec& L = Ls[l];
      const float* bias = (const float*)d_in[3 + 3 * l];
      dim3 gg((L.NtG + 15) / 16, (unsigned)(RC / 16));
      hipLaunchKernelGGL(gemm_mfma, gg, dim3(256), 0, stream,
                         Ag[l], sAg[l], L.KactG, gemB[l], bias, xp,
                         L.N, L.NtG, L.KsG, (l == 0) ? t0 : -1, tcLog2);
      const float* brec = bias + L.N;
      if (l == 0) {
        hipLaunchKernelGGL(rec_l1, dim3(16), dim3(256), 0, stream,
                           xp, recB[0], brec, hbuf1, y1c,
                           flags + (size_t)c * 64, t0, Tc, (c == 0) ? 1 : 0);
      } else {
        hipLaunchKernelGGL(rec_single, dim3(1), dim3(snthr[l]), 0, stream,
                           xp, recB[l], brec, hsv[l], Ob[l], sOb[l], Of[l], sOf[l],
                           L.U, L.Kpad, L.KsR, L.JT, sjpw[l], L.act, t0, Tc,
                           (c == 0) ? 1 : 0);
      }
    }
  }
}

// Round 7
// 17992.265 us; speedup vs baseline: 3.3951x; 1.2506x over previous
//
#include <hip/hip_runtime.h>
#include <hip/hip_bf16.h>
#include <cstdint>
#include <cstddef>

#define BB 32
#define TT 512

typedef short s8v __attribute__((ext_vector_type(8)));
typedef float f4v __attribute__((ext_vector_type(4)));
typedef unsigned long long u64;
typedef unsigned short u16;
typedef unsigned int u32;

__device__ __forceinline__ short f2b(float x) {
  __hip_bfloat16 h = __float2bfloat16(x);
  return *reinterpret_cast<short*>(&h);
}
__device__ __forceinline__ float b2f(u16 x) {
  __hip_bfloat16 h = *reinterpret_cast<__hip_bfloat16*>(&x);
  return __bfloat162float(h);
}
__device__ __forceinline__ float sigm(float x) { return 1.f / (1.f + __expf(-x)); }

// LLC-coherent pipelined 16B load; caller must vm_wait0() before use.
__device__ __forceinline__ f4v load16_sc(const void* p) {
  f4v v;
  asm volatile("global_load_dwordx4 %0, %1, off sc0 sc1" : "=v"(v) : "v"(p));
  return v;
}
__device__ __forceinline__ void vm_wait0() {
  asm volatile("s_waitcnt vmcnt(0)" ::: "memory");
}
__device__ __forceinline__ u32 ldP(const u32* p) {
  return __hip_atomic_load(p, __ATOMIC_RELAXED, __HIP_MEMORY_SCOPE_AGENT);
}
__device__ __forceinline__ void stP(u32* p, u32 v) {
  __hip_atomic_store(p, v, __ATOMIC_RELEASE, __HIP_MEMORY_SCOPE_AGENT);
}
__device__ __forceinline__ void stW(u32* p, u32 v) {
  __hip_atomic_store(p, v, __ATOMIC_RELAXED, __HIP_MEMORY_SCOPE_AGENT);
}
__device__ __forceinline__ u32 ldW(const u32* p) {
  return __hip_atomic_load(p, __ATOMIC_RELAXED, __HIP_MEMORY_SCOPE_AGENT);
}

// block-wide wait: flags[baseA+i] >= thA (i<na), flags[baseB+i] >= thB, flags[baseS+i] >= thS
__device__ __forceinline__ void waitP(u32* flags, int baseA, int na, u32 thA,
                                      int baseB, int nbb, u32 thB,
                                      int baseS, int ns, u32 thS) {
  const int tid = threadIdx.x;
  for (;;) {
    int ok = 1;
    if (tid < na) ok = (ldP(&flags[baseA + tid]) >= thA) ? 1 : 0;
    else if (tid < na + nbb) ok = (ldP(&flags[baseB + tid - na]) >= thB) ? 1 : 0;
    else if (tid < na + nbb + ns) ok = (ldP(&flags[baseS + tid - na - nbb]) >= thS) ? 1 : 0;
    if (__syncthreads_count(ok) == 512) break;
    __builtin_amdgcn_s_sleep(1);
  }
}

// ---------------- x -> bf16 cast ----------------
__global__ __launch_bounds__(256) void cast_bf16(const float* __restrict__ in,
                                                 u16* __restrict__ outp, int n4) {
  int i = blockIdx.x * 256 + threadIdx.x;
  if (i < n4) {
    float4 v = *(const float4*)(in + (size_t)i * 4);
    u16 o[4] = {(u16)f2b(v.x), (u16)f2b(v.y), (u16)f2b(v.z), (u16)f2b(v.w)};
    *(u64*)(outp + (size_t)i * 4) = *(const u64*)o;
  }
}

// ---------------- weight -> MFMA B-fragment order (L1 rec + L1 gemm) ----------------
__global__ __launch_bounds__(256) void prep_frags(const float* __restrict__ src,
                                                  u16* __restrict__ dst,
                                                  int N, int Ksrc, int Ks,
                                                  int JT, int U, int recmode, int total_fid) {
  int t = blockIdx.x * 256 + threadIdx.x;
  int lane = t & 63, fid = t >> 6;
  if (fid >= total_fid) return;
  int l15 = lane & 15, quad = lane >> 4;
  int ks = fid % Ks;
  int n, valid_n;
  if (recmode) {
    int rest = fid / Ks;
    int jt = rest % JT;
    int g = rest / JT;
    int jj = jt * 16 + l15;
    n = g * U + jj;
    valid_n = (jj < U) ? 1 : 0;
  } else {
    int nt = fid / Ks;
    n = nt * 16 + l15;
    valid_n = (n < N) ? 1 : 0;
  }
  u16* o = dst + ((size_t)fid * 64 + lane) * 8;
#pragma unroll
  for (int j = 0; j < 8; ++j) {
    int k = ks * 32 + quad * 8 + j;
    float v = (valid_n && k < Ksrc) ? src[(size_t)k * N + n] : 0.f;
    o[j] = (u16)f2b(v);
  }
}

// ---------------- combined [K-input | K-input2 | R] fragged weights (stages 2..6) -----
__global__ __launch_bounds__(256) void prep_comb(const float* __restrict__ Kmat,
                                                 const float* __restrict__ Rmat,
                                                 u16* __restrict__ dst,
                                                 int N, int U, int w1v, int w1p,
                                                 int w2v, int w2p, int Ks, int JT,
                                                 int total_fid) {
  int t = blockIdx.x * 256 + threadIdx.x;
  int lane = t & 63, fid = t >> 6;
  if (fid >= total_fid) return;
  int l15 = lane & 15, quad = lane >> 4;
  int ks = fid % Ks;
  int rest = fid / Ks;
  int jt = rest % JT;
  int g = rest / JT;
  int j = jt * 16 + l15;
  bool jv = (j < U);
  int n = g * U + (jv ? j : 0);
  u16* o = dst + ((size_t)fid * 64 + lane) * 8;
#pragma unroll
  for (int jj = 0; jj < 8; ++jj) {
    int k = ks * 32 + quad * 8 + jj;
    float v = 0.f;
    if (jv) {
      if (k < w1p) {
        if (k < w1v) v = Kmat[(size_t)k * N + n];
      } else if (k < w1p + w2p) {
        int kr = k - w1p;
        if (kr < w2v) v = Kmat[(size_t)(w1v + kr) * N + n];
      } else {
        int rr = k - w1p - w2p;
        if (rr < U) v = Rmat[(size_t)rr * N + n];
      }
    }
    o[jj] = (u16)f2b(v);
  }
}

// ---------------- MFMA GEMM (L1 xp only): C[M,3072] = A[M,512]bf16 @ W + bias -------
__global__ __launch_bounds__(256) void gemm_mfma(const u16* __restrict__ A, int strideA, int Kact,
                                                 const u16* __restrict__ Bf,
                                                 const float* __restrict__ bias,
                                                 float* __restrict__ C,
                                                 int N, int Ntiles, int Ks,
                                                 int t0, int tcLog2) {
  __shared__ char sha[16 * 2056];
  const int tid = threadIdx.x;
  const int lane = tid & 63, l15 = lane & 15, quad = lane >> 4, w = tid >> 6;
  const int KS4 = Ks * 8;
  const int rowB = Ks * 64 + 8;
  const int bm = blockIdx.y * 16;

  for (int i = tid; i < 16 * KS4; i += 256) {
    int r = i / KS4, u = i - r * KS4;
    u64 v = 0;
    if (u * 4 < Kact) {
      int rl = bm + r;
      size_t grow;
      if (t0 >= 0) {
        int tcm = (1 << tcLog2) - 1;
        grow = (((size_t)(rl >> tcLog2)) << 9) + t0 + (rl & tcm);
      } else {
        grow = (size_t)rl;
      }
      v = *((const u64*)(A + grow * (size_t)strideA) + u);
    }
    *(u64*)(sha + r * rowB + u * 8) = v;
  }
  __syncthreads();

  f4v acc[4];
  f4v z4 = {0.f, 0.f, 0.f, 0.f};
#pragma unroll
  for (int q = 0; q < 4; ++q) acc[q] = z4;

  const int ntb = blockIdx.x * 16 + w * 4;
  for (int ks = 0; ks < Ks; ++ks) {
    int off = l15 * rowB + ks * 64 + quad * 16;
    s8v a = *(const s8v*)(sha + off);
#pragma unroll
    for (int q = 0; q < 4; ++q) {
      int nt = ntb + q;
      if (nt < Ntiles) {
        s8v b = *(const s8v*)(Bf + (((size_t)nt * Ks + ks) * 64 + lane) * 8);
        acc[q] = __builtin_amdgcn_mfma_f32_16x16x32_bf16(a, b, acc[q], 0, 0, 0);
      }
    }
  }
#pragma unroll
  for (int q = 0; q < 4; ++q) {
    int nt = ntb + q;
    if (nt >= Ntiles) continue;
    int col = nt * 16 + l15;
    if (col < N) {
      float bv = bias[col];
#pragma unroll
      for (int r = 0; r < 4; ++r) {
        int rowl = bm + quad * 4 + r;
        C[(size_t)rowl * N + col] = acc[q][r] + bv;
      }
    }
  }
}

// ---------------- generic stage config ----------------
struct GCfg {
  const u16 *s1, *s2;        // input row-buffers [row][w?p] bf16
  const u16* Bf;             // combined fragged weights
  const float* bias;         // [2][3U]
  u16* ydst;                 // bf16 out rows [row][Upad] (or null)
  float* fdst;               // fp32 out (or null)
  u16* hglob;                // nb>1: [2][32][Upad] LLC; nb==1: hsave [32][Upad]
  int w1p, w2p, Upad, U, Ks, ksIn, JT, nb, base, act, wfd;
  int baseA, na, baseB, nbb; // producer flag polls (>= t+1)
};

#define SMEM_BYTES 91648
#define HPOFF 74240

// ---------------- stage L1: 16 blocks x 512 thr; waves 0-3 compute (jt, both Mt) ----
__device__ __attribute__((noinline)) void stage_l1(
    const float* xp, const u16* Bf, const float* brec, u16* hbuf, u16* yout,
    u32* flags, int t0, int tc, char* smem) {
  const int tid = threadIdx.x;
  const int lane = tid & 63, l15 = lane & 15, quad = (lane >> 4) & 3;
  const int w = tid >> 6;
  const int blk = blockIdx.x;
  const bool work = (w < 4);
  const int jt = blk * 4 + (w & 3);
  const int j = jt * 16 + l15;
  const int HP = 32 * 1024;

  const float bz = brec[j], brr = brec[1024 + j], bh = brec[2048 + j];
  float hprev[8];
  if (work) {
    const u32* hp = (const u32*)(hbuf + (size_t)(t0 & 1) * HP);
#pragma unroll
    for (int Mt = 0; Mt < 2; ++Mt)
#pragma unroll
      for (int r = 0; r < 4; ++r) {
        int b = Mt * 16 + quad * 4 + r;
        u32 wd = ldW(hp + ((b * 1024 + (j & ~1)) >> 1));
        hprev[Mt * 4 + r] = b2f((j & 1) ? (u16)(wd >> 16) : (u16)(wd & 0xffff));
      }
  }

  for (int tt = 0; tt < tc; ++tt) {
    const int t = t0 + tt;
    waitP(flags, 0, 16, (u32)t, 0, 0, 0, 0, 0, 0);
    // xp prefetch (NT: keep L2 clean for weights)
    float xv[3][8];
    if (work) {
#pragma unroll
      for (int Mt = 0; Mt < 2; ++Mt)
#pragma unroll
        for (int r = 0; r < 4; ++r) {
          int b = Mt * 16 + quad * 4 + r;
          const float* xr_ = xp + ((size_t)b * tc + tt) * 3072;
          xv[0][Mt * 4 + r] = __builtin_nontemporal_load(xr_ + j);
          xv[1][Mt * 4 + r] = __builtin_nontemporal_load(xr_ + 1024 + j);
          xv[2][Mt * 4 + r] = __builtin_nontemporal_load(xr_ + 2048 + j);
        }
    }
    // stage h -> LDS: 4096x16B over 512 threads = 8 pipelined loads
    {
      const char* hsrc = (const char*)(hbuf + (size_t)(t & 1) * HP);
      f4v vals[8];
#pragma unroll
      for (int i = 0; i < 8; ++i)
        vals[i] = load16_sc(hsrc + (size_t)(tid + i * 512) * 16);
      vm_wait0();
#pragma unroll
      for (int i = 0; i < 8; ++i) {
        int g16 = tid + i * 512;
        *(f4v*)(smem + (g16 >> 7) * 2064 + (g16 & 127) * 16) = vals[i];
      }
    }
    __syncthreads();
    f4v acc[3][2];
    f4v z4 = {0.f, 0.f, 0.f, 0.f};
#pragma unroll
    for (int g = 0; g < 3; ++g) { acc[g][0] = z4; acc[g][1] = z4; }
    if (work) {
#pragma unroll 4
      for (int ks = 0; ks < 32; ++ks) {
        s8v a0 = *(const s8v*)(smem + l15 * 2064 + ks * 64 + quad * 16);
        s8v a1 = *(const s8v*)(smem + (16 + l15) * 2064 + ks * 64 + quad * 16);
#pragma unroll
        for (int g = 0; g < 3; ++g) {
          s8v b = *(const s8v*)(Bf + (((size_t)(g * 64 + jt) * 32 + ks) * 64 + lane) * 8);
          acc[g][0] = __builtin_amdgcn_mfma_f32_16x16x32_bf16(a0, b, acc[g][0], 0, 0, 0);
          acc[g][1] = __builtin_amdgcn_mfma_f32_16x16x32_bf16(a1, b, acc[g][1], 0, 0, 0);
        }
      }
    }
    if (work) {
      u16* hdst = hbuf + (size_t)((t + 1) & 1) * HP;
#pragma unroll
      for (int Mt = 0; Mt < 2; ++Mt)
#pragma unroll
        for (int r = 0; r < 4; ++r) {
          int b = Mt * 16 + quad * 4 + r;
          size_t row = (size_t)b * tc + tt;
          float z = sigm(xv[0][Mt * 4 + r] + acc[0][Mt][r] + bz);
          float rr = sigm(xv[1][Mt * 4 + r] + acc[1][Mt][r] + brr);
          float hh = fmaxf(xv[2][Mt * 4 + r] + rr * (acc[2][Mt][r] + bh), 0.f);
          float hnew = z * hprev[Mt * 4 + r] + (1.f - z) * hh;
          hprev[Mt * 4 + r] = hnew;
          float part = __shfl_xor(hnew, 1, 64);
          if ((l15 & 1) == 0) {
            u32 wd = (u32)(u16)f2b(hnew) | ((u32)(u16)f2b(part) << 16);
            stW((u32*)hdst + ((b * 1024 + j) >> 1), wd);
            stW((u32*)yout + ((row * 1024 + j) >> 1), wd);
          }
        }
    }
    __syncthreads();
    if (tid == 0) stP(&flags[blk], (u32)(t + 1));
  }
}

// ---------------- generic fused stage (L2..L6) ----------------
__device__ __attribute__((noinline)) void stage_gen(
    const GCfg& c, int bs, u32* flags, int t0, int tc, int initH, char* smem) {
  const int tid = threadIdx.x;
  const int lane = tid & 63, l15 = lane & 15, quad = (lane >> 4) & 3;
  const int w = tid >> 6;
  const int Kc = c.w1p + c.w2p + c.Upad;
  const int rowA = Kc * 2 + 16;
  const int rowH = c.Upad * 2 + 16;
  char* Ab = smem;
  char* Hp = smem + HPOFF;
  const int HB = 32 * rowH;
  const int uIn = (c.w1p + c.w2p) >> 3;
  const int uH = c.Upad >> 3;
  const int upr = uIn + ((c.nb > 1) ? uH : 0);
  const int total_units = 32 * upr;
  const int u1 = c.w1p >> 3;
  const int U = c.U;
  const int HPstride = 32 * c.Upad;  // elems per parity (nb>1)

  // tasks: task = jt*2 + mt
  const int ntask = c.JT * 2, nw = c.nb * 8;
  int tcount = 0;
  int tjt[2], tmt[2];
#pragma unroll
  for (int i = 0; i < 2; ++i) {
    int task = bs * 8 + w + i * nw;
    if (task < ntask) { tjt[tcount] = task >> 1; tmt[tcount] = task & 1; ++tcount; }
  }

  const float* b0 = c.bias;
  const float* b1 = c.bias + 3 * U;
  float bz[2], br_[2], bih[2], brh[2];
  int jl[2];
  bool jv[2];
#pragma unroll
  for (int i = 0; i < 2; ++i) {
    if (i >= tcount) { jv[i] = false; jl[i] = 0; bz[i] = br_[i] = bih[i] = brh[i] = 0.f; continue; }
    int j = tjt[i] * 16 + l15;
    jv[i] = (j < U);
    int jc = jv[i] ? j : 0;
    jl[i] = j;
    bz[i] = b0[jc] + b1[jc];
    br_[i] = b0[U + jc] + b1[U + jc];
    bih[i] = b0[2 * U + jc];
    brh[i] = b1[2 * U + jc];
  }

  // chunk init for single-block h-in-LDS
  if (c.nb == 1) {
    for (int i = tid; i < (2 * HB) >> 2; i += 512) ((u32*)Hp)[i] = 0;
    __syncthreads();
    if (!initH) {
      for (int i = tid; i < 32 * uH; i += 512) {
        int m = i / uH, u = i - m * uH;
        *(f4v*)(Hp + (t0 & 1) * HB + m * rowH + u * 16) = *((const f4v*)c.hglob + i);
      }
    }
    __syncthreads();
  }

  float hprev[2][8];
#pragma unroll
  for (int i = 0; i < 2; ++i) {
    if (i >= tcount) continue;
#pragma unroll
    for (int r = 0; r < 4; ++r) {
      int b = tmt[i] * 16 + quad * 4 + r;
      float hv;
      if (c.nb > 1) {
        u32 wd = ldW((const u32*)c.hglob + (((t0 & 1) * HPstride + b * c.Upad + (jl[i] & ~1)) >> 1));
        hv = b2f((jl[i] & 1) ? (u16)(wd >> 16) : (u16)(wd & 0xffff));
      } else {
        hv = b2f(*(const u16*)(Hp + (t0 & 1) * HB + b * rowH + jl[i] * 2));
      }
      hprev[i][r] = jv[i] ? hv : 0.f;
    }
  }

  for (int tt = 0; tt < tc; ++tt) {
    const int t = t0 + tt;
    waitP(flags, c.baseA, c.na, (u32)(t + 1), c.baseB, c.nbb, (u32)(t + 1),
          c.base, (c.nb > 1) ? c.nb : 0, (u32)t);
    // ---- stage A (inputs [+h if nb>1]) into LDS ----
    {
      f4v vals[12];
      int offs[12];
#pragma unroll
      for (int i = 0; i < 12; ++i) {
        int idx = tid + i * 512;
        int pidx = (idx < total_units) ? idx : (total_units - 1);
        int m = pidx / upr, u = pidx - m * upr;
        const char* src;
        if (u < u1)
          src = (const char*)c.s1 + ((size_t)(m * tc + tt) * c.w1p + (u << 3)) * 2;
        else if (u < uIn)
          src = (const char*)c.s2 + ((size_t)(m * tc + tt) * c.w2p + ((u - u1) << 3)) * 2;
        else
          src = (const char*)c.hglob + ((size_t)(t & 1) * HPstride + m * c.Upad + ((u - uIn) << 3)) * 2;
        vals[i] = load16_sc(src);
        offs[i] = m * rowA + u * 16;
      }
      vm_wait0();
#pragma unroll
      for (int i = 0; i < 12; ++i)
        if (tid + i * 512 < total_units) *(f4v*)(Ab + offs[i]) = vals[i];
    }
    __syncthreads();
    // ---- MFMA: input-K part (z,r,xh), then h part (z,r,rh) ----
    f4v az[2], ar[2], axh[2], arh[2];
    f4v z4 = {0.f, 0.f, 0.f, 0.f};
#pragma unroll
    for (int i = 0; i < 2; ++i) { az[i] = z4; ar[i] = z4; axh[i] = z4; arh[i] = z4; }
    for (int ks = 0; ks < c.ksIn; ++ks) {
#pragma unroll
      for (int i = 0; i < 2; ++i) {
        if (i >= tcount) break;
        s8v a = *(const s8v*)(Ab + (tmt[i] * 16 + l15) * rowA + ks * 64 + quad * 16);
        const u16* bb = c.Bf + ((size_t)tjt[i] * c.Ks + ks) * 512 + lane * 8;
        s8v bz_ = *(const s8v*)(bb);
        s8v br2 = *(const s8v*)(bb + (size_t)c.JT * c.Ks * 512);
        s8v bh2 = *(const s8v*)(bb + (size_t)2 * c.JT * c.Ks * 512);
        az[i] = __builtin_amdgcn_mfma_f32_16x16x32_bf16(a, bz_, az[i], 0, 0, 0);
        ar[i] = __builtin_amdgcn_mfma_f32_16x16x32_bf16(a, br2, ar[i], 0, 0, 0);
        axh[i] = __builtin_amdgcn_mfma_f32_16x16x32_bf16(a, bh2, axh[i], 0, 0, 0);
      }
    }
    for (int ks = c.ksIn; ks < c.Ks; ++ks) {
#pragma unroll
      for (int i = 0; i < 2; ++i) {
        if (i >= tcount) break;
        s8v a;
        if (c.nb > 1)
          a = *(const s8v*)(Ab + (tmt[i] * 16 + l15) * rowA + ks * 64 + quad * 16);
        else
          a = *(const s8v*)(Hp + (t & 1) * HB + (tmt[i] * 16 + l15) * rowH + (ks - c.ksIn) * 64 + quad * 16);
        const u16* bb = c.Bf + ((size_t)tjt[i] * c.Ks + ks) * 512 + lane * 8;
        s8v bz_ = *(const s8v*)(bb);
        s8v br2 = *(const s8v*)(bb + (size_t)c.JT * c.Ks * 512);
        s8v bh2 = *(const s8v*)(bb + (size_t)2 * c.JT * c.Ks * 512);
        az[i] = __builtin_amdgcn_mfma_f32_16x16x32_bf16(a, bz_, az[i], 0, 0, 0);
        ar[i] = __builtin_amdgcn_mfma_f32_16x16x32_bf16(a, br2, ar[i], 0, 0, 0);
        arh[i] = __builtin_amdgcn_mfma_f32_16x16x32_bf16(a, bh2, arh[i], 0, 0, 0);
      }
    }
    // ---- gates + publish ----
#pragma unroll
    for (int i = 0; i < 2; ++i) {
      if (i >= tcount) break;
#pragma unroll
      for (int r = 0; r < 4; ++r) {
        int b = tmt[i] * 16 + quad * 4 + r;
        size_t row = (size_t)b * tc + tt;
        float z = sigm(az[i][r] + bz[i]);
        float rg = sigm(ar[i][r] + br_[i]);
        float hh = axh[i][r] + bih[i] + rg * (arh[i][r] + brh[i]);
        if (c.act) hh = fmaxf(hh, 0.f);
        float hnew = z * hprev[i][r] + (1.f - z) * hh;
        if (!jv[i]) hnew = 0.f;
        hprev[i][r] = hnew;
        int j = jl[i];
        float part = __shfl_xor(hnew, 1, 64);
        u32 wd = (u32)(u16)f2b(hnew) | ((u32)(u16)f2b(part) << 16);
        if ((l15 & 1) == 0) {
          if (c.ydst) stW((u32*)c.ydst + ((row * c.Upad + j) >> 1), wd);
          if (c.nb > 1)
            stW((u32*)c.hglob + ((((t + 1) & 1) * HPstride + b * c.Upad + j) >> 1), wd);
        }
        if (c.nb == 1) *(u16*)(Hp + ((t + 1) & 1) * HB + b * rowH + j * 2) = (u16)f2b(hnew);
        if (c.fdst && jv[i] && j < c.wfd)
          c.fdst[((size_t)b * TT + t) * c.wfd + j] = hnew;
      }
    }
    __syncthreads();
    if (tid == 0) stP(&flags[c.base + bs], (u32)(t + 1));
  }
  // chunk-end save (single-block h)
  if (c.nb == 1) {
    int pf = (t0 + tc) & 1;
    for (int i = tid; i < 32 * uH; i += 512) {
      int m = i / uH, u = i - m * uH;
      *((f4v*)c.hglob + i) = *(const f4v*)(Hp + pf * HB + m * rowH + u * 16);
    }
  }
}

// ---------------- the pipeline kernel: 23 blocks x 512 ----------------
__global__ __launch_bounds__(512, 1) void pipeline(
    const float* xp, const u16* BfL1, const float* brecL1, u16* hbufL1, u16* y1c,
    GCfg c1, GCfg c2, GCfg c3, GCfg c4, GCfg c5,
    u32* flags, int t0, int tc, int initH) {
  __shared__ char smem[SMEM_BYTES];
  int blk = blockIdx.x;
  if (blk < 16) stage_l1(xp, BfL1, brecL1, hbufL1, y1c, flags, t0, tc, smem);
  else if (blk < 18) stage_gen(c1, blk - 16, flags, t0, tc, initH, smem);
  else if (blk < 19) stage_gen(c2, 0, flags, t0, tc, initH, smem);
  else if (blk < 21) stage_gen(c3, blk - 19, flags, t0, tc, initH, smem);
  else if (blk < 22) stage_gen(c4, 0, flags, t0, tc, initH, smem);
  else stage_gen(c5, 0, flags, t0, tc, initH, smem);
}

// ---------------- host launch ----------------
extern "C" void kernel_launch(void* const* d_in, const int* in_sizes, int n_in,
                              void* d_out, int out_size, void* d_ws, size_t ws_size,
                              hipStream_t stream) {
  const float* x = (const float*)d_in[0];

  // chunk size
  int tcLog2 = 6;
  {
    size_t fixed = (size_t)16384 * 512 * 2            // x16
                   + (3145728ull + 1572864ull + 442368 + 15360 + 319488 + 147456 + 7680) * 2
                   + 300000;                          // frags + slack
    for (; tcLog2 >= 4; --tcLog2) {
      size_t rc = (size_t)BB << tcLog2;
      size_t per = rc * 3072 * 4 + rc * (1024 + 128 + 32 + 256 + 128) * 2 + 8192;
      if (fixed + per <= ws_size || tcLog2 == 4) break;
    }
  }
  const int Tc = 1 << tcLog2;
  const int NCk = TT / Tc;
  const size_t RC = (size_t)BB * Tc;

  char* ws = (char*)d_ws;
  size_t off = 0;
  auto alloc = [&](size_t bytes) -> char* {
    char* p = ws + off;
    off += (bytes + 255) & ~(size_t)255;
    return p;
  };

  u32* flags = (u32*)alloc(64 * sizeof(u32));
  u16* hbufL1 = (u16*)alloc((size_t)2 * 32 * 1024 * 2);
  u16* hb2 = (u16*)alloc((size_t)2 * 32 * 128 * 2);   // stage1 (L2) LLC h
  u16* hb4 = (u16*)alloc((size_t)2 * 32 * 256 * 2);   // stage3 (L4) LLC h
  u16* hs3 = (u16*)alloc((size_t)32 * 32 * 2);        // L3 hsave
  u16* hs5 = (u16*)alloc((size_t)32 * 128 * 2);       // L5 hsave
  u16* hs6 = (u16*)alloc((size_t)32 * 32 * 2);        // L6 hsave
  u16* recB1 = (u16*)alloc(3145728ull * 2);
  u16* gemB1 = (u16*)alloc(1572864ull * 2);
  u16* cB[5];
  const size_t cBe[5] = {442368, 15360, 319488, 147456, 7680};
  for (int i = 0; i < 5; ++i) cB[i] = (u16*)alloc(cBe[i] * 2);
  u16* x16 = (u16*)alloc((size_t)16384 * 512 * 2);
  float* xp = (float*)alloc(RC * 3072 * sizeof(float));
  u16* y1c = (u16*)alloc(RC * 1024 * 2);
  u16* y2c = (u16*)alloc(RC * 128 * 2);
  u16* yec = (u16*)alloc(RC * 32 * 2);
  u16* y4c = (u16*)alloc(RC * 256 * 2);
  u16* y5c = (u16*)alloc(RC * 128 * 2);

  float* outye = (float*)d_out;
  float* outyd = outye + (size_t)BB * TT * 23;

  hipMemsetAsync(flags, 0, 64 * sizeof(u32), stream);
  hipMemsetAsync(hbufL1, 0, (size_t)2 * 32 * 1024 * 2, stream);
  hipMemsetAsync(hb2, 0, (size_t)2 * 32 * 128 * 2, stream);
  hipMemsetAsync(hb4, 0, (size_t)2 * 32 * 256 * 2, stream);

  // ---- prep ----
  {
    int n4 = (16384 * 512) / 4;
    hipLaunchKernelGGL(cast_bf16, dim3((n4 + 255) / 256), dim3(256), 0, stream, x, x16, n4);
    // L1 recurrent frags (JT=64, Ks=32) + L1 gemm frags (Nt=192, Ks=16)
    hipLaunchKernelGGL(prep_frags, dim3((3 * 64 * 32 * 64 + 255) / 256), dim3(256), 0, stream,
                       (const float*)d_in[2], recB1, 3072, 1024, 32, 64, 1024, 1, 3 * 64 * 32);
    hipLaunchKernelGGL(prep_frags, dim3((192 * 16 * 64 + 255) / 256), dim3(256), 0, stream,
                       (const float*)d_in[1], gemB1, 3072, 512, 16, 0, 0, 0, 192 * 16);
    // combined frags stages 2..6: N, U, w1v, w1p, w2v, w2p, Ks, JT
    const int pc[5][8] = {
        {384, 128, 1024, 1024, 0, 0, 36, 8},   // L2
        {69, 23, 128, 128, 0, 0, 5, 2},        // L3
        {768, 256, 128, 128, 23, 32, 13, 16},  // L4
        {384, 128, 256, 256, 0, 0, 12, 8},     // L5
        {24, 8, 128, 128, 0, 0, 5, 1}};        // L6
    for (int i = 0; i < 5; ++i) {
      int l = i + 1;
      int tf = 3 * pc[i][7] * pc[i][6];
      hipLaunchKernelGGL(prep_comb, dim3((tf * 64 + 255) / 256), dim3(256), 0, stream,
                         (const float*)d_in[1 + 3 * l], (const float*)d_in[2 + 3 * l], cB[i],
                         pc[i][0], pc[i][1], pc[i][2], pc[i][3], pc[i][4], pc[i][5],
                         pc[i][6], pc[i][7], tf);
    }
  }

  // ---- stage configs ----
  GCfg c1 = {y1c, nullptr, cB[0], (const float*)d_in[6], y2c, nullptr, hb2,
             1024, 0, 128, 128, 36, 32, 8, 2, 16, 1, 0, 0, 16, 0, 0};
  GCfg c2 = {y2c, nullptr, cB[1], (const float*)d_in[9], yec, outye, hs3,
             128, 0, 32, 23, 5, 4, 2, 1, 18, 0, 23, 16, 2, 0, 0};
  GCfg c3 = {y2c, yec, cB[2], (const float*)d_in[12], y4c, nullptr, hb4,
             128, 32, 256, 256, 13, 5, 16, 2, 19, 1, 0, 16, 2, 18, 1};
  GCfg c4 = {y4c, nullptr, cB[3], (const float*)d_in[15], y5c, nullptr, hs5,
             256, 0, 128, 128, 12, 8, 8, 1, 21, 1, 0, 19, 2, 0, 0};
  GCfg c5 = {y5c, nullptr, cB[4], (const float*)d_in[18], nullptr, outyd, hs6,
             128, 0, 32, 8, 5, 4, 1, 1, 22, 0, 8, 21, 1, 0, 0};

  const float* biasL1 = (const float*)d_in[3];

  for (int c = 0; c < NCk; ++c) {
    const int t0 = c * Tc;
    hipLaunchKernelGGL(gemm_mfma, dim3(12, (unsigned)(RC / 16)), dim3(256), 0, stream,
                       x16, 512, 512, gemB1, biasL1, xp, 3072, 192, 16, t0, tcLog2);
    hipLaunchKernelGGL(pipeline, dim3(23), dim3(512), 0, stream,
                       xp, recB1, biasL1 + 3072, hbufL1, y1c,
                       c1, c2, c3, c4, c5, flags, t0, Tc, (c == 0) ? 1 : 0);
  }
}

// Round 8
// 15686.415 us; speedup vs baseline: 3.8942x; 1.1470x over previous
//
#include <hip/hip_runtime.h>
#include <hip/hip_bf16.h>
#include <cstdint>
#include <cstddef>

#define BB 32
#define TT 512

typedef short s8v __attribute__((ext_vector_type(8)));
typedef float f4v __attribute__((ext_vector_type(4)));
typedef unsigned long long u64;
typedef unsigned short u16;
typedef unsigned int u32;

__device__ __forceinline__ short f2b(float x) {
  __hip_bfloat16 h = __float2bfloat16(x);
  return *reinterpret_cast<short*>(&h);
}
__device__ __forceinline__ float b2f(u16 x) {
  __hip_bfloat16 h = *reinterpret_cast<__hip_bfloat16*>(&x);
  return __bfloat162float(h);
}
__device__ __forceinline__ float sigm(float x) { return 1.f / (1.f + __expf(-x)); }

// LLC-coherent pipelined 16B load; caller must vm_wait0() before use.
__device__ __forceinline__ f4v load16_sc(const void* p) {
  f4v v;
  asm volatile("global_load_dwordx4 %0, %1, off sc0 sc1" : "=v"(v) : "v"(p));
  return v;
}
__device__ __forceinline__ void vm_wait0() {
  asm volatile("s_waitcnt vmcnt(0)" ::: "memory");
}
__device__ __forceinline__ u32 ldP(const u32* p) {
  return __hip_atomic_load(p, __ATOMIC_RELAXED, __HIP_MEMORY_SCOPE_AGENT);
}
__device__ __forceinline__ void stP(u32* p, u32 v) {
  __hip_atomic_store(p, v, __ATOMIC_RELEASE, __HIP_MEMORY_SCOPE_AGENT);
}
__device__ __forceinline__ void stW(u32* p, u32 v) {
  __hip_atomic_store(p, v, __ATOMIC_RELAXED, __HIP_MEMORY_SCOPE_AGENT);
}
__device__ __forceinline__ u32 ldW(const u32* p) {
  return __hip_atomic_load(p, __ATOMIC_RELAXED, __HIP_MEMORY_SCOPE_AGENT);
}

// Flags are padded: slot i lives at flags[i*32] (one 128B line each) — avoids
// LLC same-line serialization between pollers and producers (the R7 stall).
__device__ __forceinline__ void waitP(u32* flags, int baseA, int na, u32 thA,
                                      int baseB, int nbb, u32 thB,
                                      int baseS, int ns, u32 thS) {
  const int tid = threadIdx.x;
  for (;;) {
    int ok = 1;
    if (tid < na) ok = (ldP(&flags[(baseA + tid) * 32]) >= thA) ? 1 : 0;
    else if (tid < na + nbb) ok = (ldP(&flags[(baseB + tid - na) * 32]) >= thB) ? 1 : 0;
    else if (tid < na + nbb + ns) ok = (ldP(&flags[(baseS + tid - na - nbb) * 32]) >= thS) ? 1 : 0;
    if (__syncthreads_count(ok) == (int)blockDim.x) break;
    __builtin_amdgcn_s_sleep(1);
  }
}

// ---------------- x -> bf16 cast ----------------
__global__ __launch_bounds__(256) void cast_bf16(const float* __restrict__ in,
                                                 u16* __restrict__ outp, int n4) {
  int i = blockIdx.x * 256 + threadIdx.x;
  if (i < n4) {
    float4 v = *(const float4*)(in + (size_t)i * 4);
    u16 o[4] = {(u16)f2b(v.x), (u16)f2b(v.y), (u16)f2b(v.z), (u16)f2b(v.w)};
    *(u64*)(outp + (size_t)i * 4) = *(const u64*)o;
  }
}

// ---------------- weight -> MFMA B-fragment order (L1 rec + L1 gemm) ----------------
__global__ __launch_bounds__(256) void prep_frags(const float* __restrict__ src,
                                                  u16* __restrict__ dst,
                                                  int N, int Ksrc, int Ks,
                                                  int JT, int U, int recmode, int total_fid) {
  int t = blockIdx.x * 256 + threadIdx.x;
  int lane = t & 63, fid = t >> 6;
  if (fid >= total_fid) return;
  int l15 = lane & 15, quad = lane >> 4;
  int ks = fid % Ks;
  int n, valid_n;
  if (recmode) {
    int rest = fid / Ks;
    int jt = rest % JT;
    int g = rest / JT;
    int jj = jt * 16 + l15;
    n = g * U + jj;
    valid_n = (jj < U) ? 1 : 0;
  } else {
    int nt = fid / Ks;
    n = nt * 16 + l15;
    valid_n = (n < N) ? 1 : 0;
  }
  u16* o = dst + ((size_t)fid * 64 + lane) * 8;
#pragma unroll
  for (int j = 0; j < 8; ++j) {
    int k = ks * 32 + quad * 8 + j;
    float v = (valid_n && k < Ksrc) ? src[(size_t)k * N + n] : 0.f;
    o[j] = (u16)f2b(v);
  }
}

// ---------------- combined [K-input | K-input2 | R] fragged weights (stages 2..6) -----
__global__ __launch_bounds__(256) void prep_comb(const float* __restrict__ Kmat,
                                                 const float* __restrict__ Rmat,
                                                 u16* __restrict__ dst,
                                                 int N, int U, int w1v, int w1p,
                                                 int w2v, int w2p, int Ks, int JT,
                                                 int total_fid) {
  int t = blockIdx.x * 256 + threadIdx.x;
  int lane = t & 63, fid = t >> 6;
  if (fid >= total_fid) return;
  int l15 = lane & 15, quad = lane >> 4;
  int ks = fid % Ks;
  int rest = fid / Ks;
  int jt = rest % JT;
  int g = rest / JT;
  int j = jt * 16 + l15;
  bool jv = (j < U);
  int n = g * U + (jv ? j : 0);
  u16* o = dst + ((size_t)fid * 64 + lane) * 8;
#pragma unroll
  for (int jj = 0; jj < 8; ++jj) {
    int k = ks * 32 + quad * 8 + jj;
    float v = 0.f;
    if (jv) {
      if (k < w1p) {
        if (k < w1v) v = Kmat[(size_t)k * N + n];
      } else if (k < w1p + w2p) {
        int kr = k - w1p;
        if (kr < w2v) v = Kmat[(size_t)(w1v + kr) * N + n];
      } else {
        int rr = k - w1p - w2p;
        if (rr < U) v = Rmat[(size_t)rr * N + n];
      }
    }
    o[jj] = (u16)f2b(v);
  }
}

// ---------------- MFMA GEMM (L1 xp only): C[M,3072] = A[M,512]bf16 @ W + bias -------
__global__ __launch_bounds__(256) void gemm_mfma(const u16* __restrict__ A, int strideA, int Kact,
                                                 const u16* __restrict__ Bf,
                                                 const float* __restrict__ bias,
                                                 float* __restrict__ C,
                                                 int N, int Ntiles, int Ks,
                                                 int t0, int tcLog2) {
  __shared__ char sha[16 * 2056];
  const int tid = threadIdx.x;
  const int lane = tid & 63, l15 = lane & 15, quad = lane >> 4, w = tid >> 6;
  const int KS4 = Ks * 8;
  const int rowB = Ks * 64 + 8;
  const int bm = blockIdx.y * 16;

  for (int i = tid; i < 16 * KS4; i += 256) {
    int r = i / KS4, u = i - r * KS4;
    u64 v = 0;
    if (u * 4 < Kact) {
      int rl = bm + r;
      size_t grow;
      if (t0 >= 0) {
        int tcm = (1 << tcLog2) - 1;
        grow = (((size_t)(rl >> tcLog2)) << 9) + t0 + (rl & tcm);
      } else {
        grow = (size_t)rl;
      }
      v = *((const u64*)(A + grow * (size_t)strideA) + u);
    }
    *(u64*)(sha + r * rowB + u * 8) = v;
  }
  __syncthreads();

  f4v acc[4];
  f4v z4 = {0.f, 0.f, 0.f, 0.f};
#pragma unroll
  for (int q = 0; q < 4; ++q) acc[q] = z4;

  const int ntb = blockIdx.x * 16 + w * 4;
  for (int ks = 0; ks < Ks; ++ks) {
    int off = l15 * rowB + ks * 64 + quad * 16;
    s8v a = *(const s8v*)(sha + off);
#pragma unroll
    for (int q = 0; q < 4; ++q) {
      int nt = ntb + q;
      if (nt < Ntiles) {
        s8v b = *(const s8v*)(Bf + (((size_t)nt * Ks + ks) * 64 + lane) * 8);
        acc[q] = __builtin_amdgcn_mfma_f32_16x16x32_bf16(a, b, acc[q], 0, 0, 0);
      }
    }
  }
#pragma unroll
  for (int q = 0; q < 4; ++q) {
    int nt = ntb + q;
    if (nt >= Ntiles) continue;
    int col = nt * 16 + l15;
    if (col < N) {
      float bv = bias[col];
#pragma unroll
      for (int r = 0; r < 4; ++r) {
        int rowl = bm + quad * 4 + r;
        C[(size_t)rowl * N + col] = acc[q][r] + bv;
      }
    }
  }
}

// ---------------- generic stage config ----------------
struct GCfg {
  const u16 *s1, *s2;        // input row-buffers [row][w?p] bf16
  const u16* Bf;             // combined fragged weights
  const float* bias;         // [2][3U]
  u16* ydst;                 // bf16 out rows [row][Upad] (or null)
  float* fdst;               // fp32 out (or null)
  u16* hglob;                // nb>1: [2][32][Upad] LLC; nb==1: hsave [32][Upad]
  int w1p, w2p, Upad, U, Ks, ksIn, JT, nb, base, act, wfd;
  int baseA, na, baseB, nbb; // producer flag polls (>= t+1)
};

#define SMEM_BYTES 91648
#define HPOFF 74240

// ---------------- stage L1: 8 blocks x 1024 thr; wave = one (jt,Mt) task ----------
__device__ __attribute__((noinline)) void stage_l1(
    const float* xp, const u16* Bf, const float* brec, u16* hbuf, u16* yout,
    u32* flags, int t0, int tc, char* smem) {
  const int tid = threadIdx.x;
  const int lane = tid & 63, l15 = lane & 15, quad = (lane >> 4) & 3;
  const int w = tid >> 6;             // 0..15
  const int blk = blockIdx.x;         // 0..7
  const int jt = blk * 8 + (w & 7);
  const int Mt = w >> 3;
  const int j = jt * 16 + l15;
  const int HP = 32 * 1024;

  const float bz = brec[j], brr = brec[1024 + j], bh = brec[2048 + j];
  float hprev[4];
  {
    const u32* hp = (const u32*)(hbuf + (size_t)(t0 & 1) * HP);
#pragma unroll
    for (int r = 0; r < 4; ++r) {
      int b = Mt * 16 + quad * 4 + r;
      u32 wd = ldW(hp + ((b * 1024 + (j & ~1)) >> 1));
      hprev[r] = b2f((j & 1) ? (u16)(wd >> 16) : (u16)(wd & 0xffff));
    }
  }

  for (int tt = 0; tt < tc; ++tt) {
    const int t = t0 + tt;
    waitP(flags, 0, 8, (u32)t, 0, 0, 0, 0, 0, 0);
    // xp prefetch (NT: keep L2 clean for weights)
    float xv[3][4];
#pragma unroll
    for (int r = 0; r < 4; ++r) {
      int b = Mt * 16 + quad * 4 + r;
      const float* xr_ = xp + ((size_t)b * tc + tt) * 3072;
      xv[0][r] = __builtin_nontemporal_load(xr_ + j);
      xv[1][r] = __builtin_nontemporal_load(xr_ + 1024 + j);
      xv[2][r] = __builtin_nontemporal_load(xr_ + 2048 + j);
    }
    // stage h -> LDS: 4096x16B over 1024 threads = 4 pipelined loads
    {
      const char* hsrc = (const char*)(hbuf + (size_t)(t & 1) * HP);
      f4v vals[4];
#pragma unroll
      for (int i = 0; i < 4; ++i)
        vals[i] = load16_sc(hsrc + (size_t)(tid + i * 1024) * 16);
      vm_wait0();
#pragma unroll
      for (int i = 0; i < 4; ++i) {
        int g16 = tid + i * 1024;
        *(f4v*)(smem + (g16 >> 7) * 2064 + (g16 & 127) * 16) = vals[i];
      }
    }
    __syncthreads();
    f4v acc[3];
    f4v z4 = {0.f, 0.f, 0.f, 0.f};
#pragma unroll
    for (int g = 0; g < 3; ++g) acc[g] = z4;
#pragma unroll 4
    for (int ks = 0; ks < 32; ++ks) {
      s8v a = *(const s8v*)(smem + (Mt * 16 + l15) * 2064 + ks * 64 + quad * 16);
#pragma unroll
      for (int g = 0; g < 3; ++g) {
        s8v b = *(const s8v*)(Bf + (((size_t)(g * 64 + jt) * 32 + ks) * 64 + lane) * 8);
        acc[g] = __builtin_amdgcn_mfma_f32_16x16x32_bf16(a, b, acc[g], 0, 0, 0);
      }
    }
    u16* hdst = hbuf + (size_t)((t + 1) & 1) * HP;
#pragma unroll
    for (int r = 0; r < 4; ++r) {
      int b = Mt * 16 + quad * 4 + r;
      size_t row = (size_t)b * tc + tt;
      float z = sigm(xv[0][r] + acc[0][r] + bz);
      float rr = sigm(xv[1][r] + acc[1][r] + brr);
      float hh = fmaxf(xv[2][r] + rr * (acc[2][r] + bh), 0.f);
      float hnew = z * hprev[r] + (1.f - z) * hh;
      hprev[r] = hnew;
      float part = __shfl_xor(hnew, 1, 64);
      if ((l15 & 1) == 0) {
        u32 wd = (u32)(u16)f2b(hnew) | ((u32)(u16)f2b(part) << 16);
        stW((u32*)hdst + ((b * 1024 + j) >> 1), wd);
        stW((u32*)yout + ((row * 1024 + j) >> 1), wd);
      }
    }
    __syncthreads();  // all waves' sc1 stores drained (vmcnt0 before barrier)
    if (tid == 0) stP(&flags[blk * 32], (u32)(t + 1));
  }
}

// ---------------- generic fused stage (L2..L6), 1024 threads ----------------
__device__ __attribute__((noinline)) void stage_gen(
    const GCfg& c, int bs, u32* flags, int t0, int tc, int initH, char* smem) {
  const int tid = threadIdx.x;
  const int lane = tid & 63, l15 = lane & 15, quad = (lane >> 4) & 3;
  const int w = tid >> 6;  // 0..15
  const int Kc = c.w1p + c.w2p + c.Upad;
  const int rowA = Kc * 2 + 16;
  const int rowH = c.Upad * 2 + 16;
  char* Ab = smem;
  char* Hp = smem + HPOFF;
  const int HB = 32 * rowH;
  const int uIn = (c.w1p + c.w2p) >> 3;
  const int uH = c.Upad >> 3;
  const int upr = uIn + ((c.nb > 1) ? uH : 0);
  const int total_units = 32 * upr;
  const int u1 = c.w1p >> 3;
  const int U = c.U;
  const int HPstride = 32 * c.Upad;

  // tasks: task = jt*2 + mt; wave picks task = w*nb + bs (+ i*16*nb)
  const int ntask = c.JT * 2;
  int tcount = 0;
  int tjt[2], tmt[2];
#pragma unroll
  for (int i = 0; i < 2; ++i) {
    int task = w * c.nb + bs + i * 16 * c.nb;
    if (task < ntask) { tjt[tcount] = task >> 1; tmt[tcount] = task & 1; ++tcount; }
  }

  const float* b0 = c.bias;
  const float* b1 = c.bias + 3 * U;
  float bz[2], br_[2], bih[2], brh[2];
  int jl[2];
  bool jv[2];
#pragma unroll
  for (int i = 0; i < 2; ++i) {
    if (i >= tcount) { jv[i] = false; jl[i] = 0; bz[i] = br_[i] = bih[i] = brh[i] = 0.f; continue; }
    int j = tjt[i] * 16 + l15;
    jv[i] = (j < U);
    int jc = jv[i] ? j : 0;
    jl[i] = j;
    bz[i] = b0[jc] + b1[jc];
    br_[i] = b0[U + jc] + b1[U + jc];
    bih[i] = b0[2 * U + jc];
    brh[i] = b1[2 * U + jc];
  }

  if (c.nb == 1) {
    for (int i = tid; i < (2 * HB) >> 2; i += 1024) ((u32*)Hp)[i] = 0;
    __syncthreads();
    if (!initH) {
      for (int i = tid; i < 32 * uH; i += 1024) {
        int m = i / uH, u = i - m * uH;
        *(f4v*)(Hp + (t0 & 1) * HB + m * rowH + u * 16) = *((const f4v*)c.hglob + i);
      }
    }
    __syncthreads();
  }

  float hprev[2][4];
#pragma unroll
  for (int i = 0; i < 2; ++i) {
    if (i >= tcount) continue;
#pragma unroll
    for (int r = 0; r < 4; ++r) {
      int b = tmt[i] * 16 + quad * 4 + r;
      float hv;
      if (c.nb > 1) {
        u32 wd = ldW((const u32*)c.hglob + (((t0 & 1) * HPstride + b * c.Upad + (jl[i] & ~1)) >> 1));
        hv = b2f((jl[i] & 1) ? (u16)(wd >> 16) : (u16)(wd & 0xffff));
      } else {
        hv = b2f(*(const u16*)(Hp + (t0 & 1) * HB + b * rowH + jl[i] * 2));
      }
      hprev[i][r] = jv[i] ? hv : 0.f;
    }
  }

  for (int tt = 0; tt < tc; ++tt) {
    const int t = t0 + tt;
    waitP(flags, c.baseA, c.na, (u32)(t + 1), c.baseB, c.nbb, (u32)(t + 1),
          c.base, (c.nb > 1) ? c.nb : 0, (u32)t);
    // ---- stage A (inputs [+h if nb>1]) into LDS ----
    {
      f4v vals[5];
      int offs[5];
#pragma unroll
      for (int i = 0; i < 5; ++i) {
        int idx = tid + i * 1024;
        int pidx = (idx < total_units) ? idx : (total_units - 1);
        int m = pidx / upr, u = pidx - m * upr;
        const char* src;
        if (u < u1)
          src = (const char*)c.s1 + ((size_t)(m * tc + tt) * c.w1p + (u << 3)) * 2;
        else if (u < uIn)
          src = (const char*)c.s2 + ((size_t)(m * tc + tt) * c.w2p + ((u - u1) << 3)) * 2;
        else
          src = (const char*)c.hglob + ((size_t)(t & 1) * HPstride + m * c.Upad + ((u - uIn) << 3)) * 2;
        vals[i] = load16_sc(src);
        offs[i] = m * rowA + u * 16;
      }
      vm_wait0();
#pragma unroll
      for (int i = 0; i < 5; ++i)
        if (tid + i * 1024 < total_units) *(f4v*)(Ab + offs[i]) = vals[i];
    }
    __syncthreads();
    // ---- MFMA: input-K part (z,r,xh), then h part (z,r,rh) ----
    f4v az[2], ar[2], axh[2], arh[2];
    f4v z4 = {0.f, 0.f, 0.f, 0.f};
#pragma unroll
    for (int i = 0; i < 2; ++i) { az[i] = z4; ar[i] = z4; axh[i] = z4; arh[i] = z4; }
    for (int ks = 0; ks < c.ksIn; ++ks) {
#pragma unroll
      for (int i = 0; i < 2; ++i) {
        if (i >= tcount) break;
        s8v a = *(const s8v*)(Ab + (tmt[i] * 16 + l15) * rowA + ks * 64 + quad * 16);
        const u16* bb = c.Bf + ((size_t)tjt[i] * c.Ks + ks) * 512 + lane * 8;
        s8v bz_ = *(const s8v*)(bb);
        s8v br2 = *(const s8v*)(bb + (size_t)c.JT * c.Ks * 512);
        s8v bh2 = *(const s8v*)(bb + (size_t)2 * c.JT * c.Ks * 512);
        az[i] = __builtin_amdgcn_mfma_f32_16x16x32_bf16(a, bz_, az[i], 0, 0, 0);
        ar[i] = __builtin_amdgcn_mfma_f32_16x16x32_bf16(a, br2, ar[i], 0, 0, 0);
        axh[i] = __builtin_amdgcn_mfma_f32_16x16x32_bf16(a, bh2, axh[i], 0, 0, 0);
      }
    }
    for (int ks = c.ksIn; ks < c.Ks; ++ks) {
#pragma unroll
      for (int i = 0; i < 2; ++i) {
        if (i >= tcount) break;
        s8v a;
        if (c.nb > 1)
          a = *(const s8v*)(Ab + (tmt[i] * 16 + l15) * rowA + ks * 64 + quad * 16);
        else
          a = *(const s8v*)(Hp + (t & 1) * HB + (tmt[i] * 16 + l15) * rowH + (ks - c.ksIn) * 64 + quad * 16);
        const u16* bb = c.Bf + ((size_t)tjt[i] * c.Ks + ks) * 512 + lane * 8;
        s8v bz_ = *(const s8v*)(bb);
        s8v br2 = *(const s8v*)(bb + (size_t)c.JT * c.Ks * 512);
        s8v bh2 = *(const s8v*)(bb + (size_t)2 * c.JT * c.Ks * 512);
        az[i] = __builtin_amdgcn_mfma_f32_16x16x32_bf16(a, bz_, az[i], 0, 0, 0);
        ar[i] = __builtin_amdgcn_mfma_f32_16x16x32_bf16(a, br2, ar[i], 0, 0, 0);
        arh[i] = __builtin_amdgcn_mfma_f32_16x16x32_bf16(a, bh2, arh[i], 0, 0, 0);
      }
    }
    // ---- gates + publish ----
#pragma unroll
    for (int i = 0; i < 2; ++i) {
      if (i >= tcount) break;
#pragma unroll
      for (int r = 0; r < 4; ++r) {
        int b = tmt[i] * 16 + quad * 4 + r;
        size_t row = (size_t)b * tc + tt;
        float z = sigm(az[i][r] + bz[i]);
        float rg = sigm(ar[i][r] + br_[i]);
        float hh = axh[i][r] + bih[i] + rg * (arh[i][r] + brh[i]);
        if (c.act) hh = fmaxf(hh, 0.f);
        float hnew = z * hprev[i][r] + (1.f - z) * hh;
        if (!jv[i]) hnew = 0.f;
        hprev[i][r] = hnew;
        int j = jl[i];
        float part = __shfl_xor(hnew, 1, 64);
        u32 wd = (u32)(u16)f2b(hnew) | ((u32)(u16)f2b(part) << 16);
        if ((l15 & 1) == 0) {
          if (c.ydst) stW((u32*)c.ydst + ((row * c.Upad + j) >> 1), wd);
          if (c.nb > 1)
            stW((u32*)c.hglob + ((((t + 1) & 1) * HPstride + b * c.Upad + j) >> 1), wd);
        }
        if (c.nb == 1) *(u16*)(Hp + ((t + 1) & 1) * HB + b * rowH + j * 2) = (u16)f2b(hnew);
        if (c.fdst && jv[i] && j < c.wfd)
          c.fdst[((size_t)b * TT + t) * c.wfd + j] = hnew;
      }
    }
    __syncthreads();
    if (tid == 0) stP(&flags[(c.base + bs) * 32], (u32)(t + 1));
  }
  if (c.nb == 1) {
    int pf = (t0 + tc) & 1;
    for (int i = tid; i < 32 * uH; i += 1024) {
      int m = i / uH, u = i - m * uH;
      *((f4v*)c.hglob + i) = *(const f4v*)(Hp + pf * HB + m * rowH + u * 16);
    }
  }
}

// ---------------- the pipeline kernel: 15 blocks x 1024 ----------------
// slots: L1=0..7, L2=8..9, L3=10, L4=11..12, L5=13, L6=14
__global__ __launch_bounds__(1024, 1) void pipeline(
    const float* xp, const u16* BfL1, const float* brecL1, u16* hbufL1, u16* y1c,
    GCfg c1, GCfg c2, GCfg c3, GCfg c4, GCfg c5,
    u32* flags, int t0, int tc, int initH) {
  __shared__ char smem[SMEM_BYTES];
  int blk = blockIdx.x;
  if (blk < 8) stage_l1(xp, BfL1, brecL1, hbufL1, y1c, flags, t0, tc, smem);
  else if (blk < 10) stage_gen(c1, blk - 8, flags, t0, tc, initH, smem);
  else if (blk < 11) stage_gen(c2, 0, flags, t0, tc, initH, smem);
  else if (blk < 13) stage_gen(c3, blk - 11, flags, t0, tc, initH, smem);
  else if (blk < 14) stage_gen(c4, 0, flags, t0, tc, initH, smem);
  else stage_gen(c5, 0, flags, t0, tc, initH, smem);
}

// ---------------- host launch ----------------
extern "C" void kernel_launch(void* const* d_in, const int* in_sizes, int n_in,
                              void* d_out, int out_size, void* d_ws, size_t ws_size,
                              hipStream_t stream) {
  const float* x = (const float*)d_in[0];

  int tcLog2 = 6;
  {
    size_t fixed = (size_t)16384 * 512 * 2
                   + (3145728ull + 1572864ull + 442368 + 15360 + 319488 + 147456 + 7680) * 2
                   + 300000;
    for (; tcLog2 >= 4; --tcLog2) {
      size_t rc = (size_t)BB << tcLog2;
      size_t per = rc * 3072 * 4 + rc * (1024 + 128 + 32 + 256 + 128) * 2 + 8192;
      if (fixed + per <= ws_size || tcLog2 == 4) break;
    }
  }
  const int Tc = 1 << tcLog2;
  const int NCk = TT / Tc;
  const size_t RC = (size_t)BB * Tc;

  char* ws = (char*)d_ws;
  size_t off = 0;
  auto alloc = [&](size_t bytes) -> char* {
    char* p = ws + off;
    off += (bytes + 255) & ~(size_t)255;
    return p;
  };

  u32* flags = (u32*)alloc(15 * 32 * sizeof(u32));
  u16* hbufL1 = (u16*)alloc((size_t)2 * 32 * 1024 * 2);
  u16* hb2 = (u16*)alloc((size_t)2 * 32 * 128 * 2);
  u16* hb4 = (u16*)alloc((size_t)2 * 32 * 256 * 2);
  u16* hs3 = (u16*)alloc((size_t)32 * 32 * 2);
  u16* hs5 = (u16*)alloc((size_t)32 * 128 * 2);
  u16* hs6 = (u16*)alloc((size_t)32 * 32 * 2);
  u16* recB1 = (u16*)alloc(3145728ull * 2);
  u16* gemB1 = (u16*)alloc(1572864ull * 2);
  u16* cB[5];
  const size_t cBe[5] = {442368, 15360, 319488, 147456, 7680};
  for (int i = 0; i < 5; ++i) cB[i] = (u16*)alloc(cBe[i] * 2);
  u16* x16 = (u16*)alloc((size_t)16384 * 512 * 2);
  float* xp = (float*)alloc(RC * 3072 * sizeof(float));
  u16* y1c = (u16*)alloc(RC * 1024 * 2);
  u16* y2c = (u16*)alloc(RC * 128 * 2);
  u16* yec = (u16*)alloc(RC * 32 * 2);
  u16* y4c = (u16*)alloc(RC * 256 * 2);
  u16* y5c = (u16*)alloc(RC * 128 * 2);

  float* outye = (float*)d_out;
  float* outyd = outye + (size_t)BB * TT * 23;

  hipMemsetAsync(flags, 0, 15 * 32 * sizeof(u32), stream);
  hipMemsetAsync(hbufL1, 0, (size_t)2 * 32 * 1024 * 2, stream);
  hipMemsetAsync(hb2, 0, (size_t)2 * 32 * 128 * 2, stream);
  hipMemsetAsync(hb4, 0, (size_t)2 * 32 * 256 * 2, stream);

  {
    int n4 = (16384 * 512) / 4;
    hipLaunchKernelGGL(cast_bf16, dim3((n4 + 255) / 256), dim3(256), 0, stream, x, x16, n4);
    hipLaunchKernelGGL(prep_frags, dim3((3 * 64 * 32 * 64 + 255) / 256), dim3(256), 0, stream,
                       (const float*)d_in[2], recB1, 3072, 1024, 32, 64, 1024, 1, 3 * 64 * 32);
    hipLaunchKernelGGL(prep_frags, dim3((192 * 16 * 64 + 255) / 256), dim3(256), 0, stream,
                       (const float*)d_in[1], gemB1, 3072, 512, 16, 0, 0, 0, 192 * 16);
    const int pc[5][8] = {
        {384, 128, 1024, 1024, 0, 0, 36, 8},   // L2
        {69, 23, 128, 128, 0, 0, 5, 2},        // L3
        {768, 256, 128, 128, 23, 32, 13, 16},  // L4
        {384, 128, 256, 256, 0, 0, 12, 8},     // L5
        {24, 8, 128, 128, 0, 0, 5, 1}};        // L6
    for (int i = 0; i < 5; ++i) {
      int l = i + 1;
      int tf = 3 * pc[i][7] * pc[i][6];
      hipLaunchKernelGGL(prep_comb, dim3((tf * 64 + 255) / 256), dim3(256), 0, stream,
                         (const float*)d_in[1 + 3 * l], (const float*)d_in[2 + 3 * l], cB[i],
                         pc[i][0], pc[i][1], pc[i][2], pc[i][3], pc[i][4], pc[i][5],
                         pc[i][6], pc[i][7], tf);
    }
  }

  // slots: L1=0..7, L2=8..9, L3=10, L4=11..12, L5=13, L6=14
  GCfg c1 = {y1c, nullptr, cB[0], (const float*)d_in[6], y2c, nullptr, hb2,
             1024, 0, 128, 128, 36, 32, 8, 2, 8, 1, 0, 0, 8, 0, 0};
  GCfg c2 = {y2c, nullptr, cB[1], (const float*)d_in[9], yec, outye, hs3,
             128, 0, 32, 23, 5, 4, 2, 1, 10, 0, 23, 8, 2, 0, 0};
  GCfg c3 = {y2c, yec, cB[2], (const float*)d_in[12], y4c, nullptr, hb4,
             128, 32, 256, 256, 13, 5, 16, 2, 11, 1, 0, 8, 2, 10, 1};
  GCfg c4 = {y4c, nullptr, cB[3], (const float*)d_in[15], y5c, nullptr, hs5,
             256, 0, 128, 128, 12, 8, 8, 1, 13, 1, 0, 11, 2, 0, 0};
  GCfg c5 = {y5c, nullptr, cB[4], (const float*)d_in[18], nullptr, outyd, hs6,
             128, 0, 32, 8, 5, 4, 1, 1, 14, 0, 8, 13, 1, 0, 0};

  const float* biasL1 = (const float*)d_in[3];

  for (int c = 0; c < NCk; ++c) {
    const int t0 = c * Tc;
    hipLaunchKernelGGL(gemm_mfma, dim3(12, (unsigned)(RC / 16)), dim3(256), 0, stream,
                       x16, 512, 512, gemB1, biasL1, xp, 3072, 192, 16, t0, tcLog2);
    hipLaunchKernelGGL(pipeline, dim3(15), dim3(1024), 0, stream,
                       xp, recB1, biasL1 + 3072, hbufL1, y1c,
                       c1, c2, c3, c4, c5, flags, t0, Tc, (c == 0) ? 1 : 0);
  }
}